// Round 11
// baseline (222.044 us; speedup 1.0000x reference)
//
#include <hip/hip_runtime.h>
#include <math.h>

// Problem constants
constexpr int B = 16, S = 100, T = 60, D = 512, H = 8, V = 32000, R = 20;
constexpr int DK = 64, WIN = 20;
constexpr int VR = V + R;        // 32020
constexpr int BT = B * T;        // 960
constexpr int MP = 1024;         // padded GEMM M
constexpr int TP = 64;           // padded T for gammaT rows
constexpr int FP = 384;          // padded B*R rows for kh GEMM

typedef unsigned short u16;
typedef unsigned int u32;
typedef __attribute__((ext_vector_type(8))) short bf16x8;
typedef __attribute__((ext_vector_type(4))) float f32x4;

__device__ __forceinline__ float wred_sum(float v) {
#pragma unroll
  for (int st = 32; st > 0; st >>= 1) v += __shfl_xor(v, st, 64);
  return v;
}
__device__ __forceinline__ float wred_max(float v) {
#pragma unroll
  for (int st = 32; st > 0; st >>= 1) v = fmaxf(v, __shfl_xor(v, st, 64));
  return v;
}
__device__ __forceinline__ float sigmoidf_(float x) { return 1.f / (1.f + expf(-x)); }
__device__ __forceinline__ u16 f2bf(float x) {
  unsigned u = __float_as_uint(x);
  return (u16)((u + 0x7fffu + ((u >> 16) & 1u)) >> 16);
}
__device__ __forceinline__ u32 cvtpk_bf16(float lo, float hi) {
  u32 r;
  asm("v_cvt_pk_bf16_f32 %0, %1, %2" : "=v"(r) : "v"(lo), "v"(hi));
  return r;
}

// ---------- vn = v·Wn[:D], vn2 = v·Wn[D:] per (b,s) ----------
__global__ void k_vn(const float* __restrict__ v, const float* __restrict__ Wn,
                     float* __restrict__ vn, float* __restrict__ vn2) {
  int row = blockIdx.x, l = threadIdx.x;           // 64 threads, B*S blocks
  const float* vr = v + (size_t)row * D + l * 8;
  float p0 = 0.f, p1 = 0.f;
#pragma unroll
  for (int i = 0; i < 8; i++) {
    float x = vr[i];
    p0 = fmaf(x, Wn[l * 8 + i], p0);
    p1 = fmaf(x, Wn[D + l * 8 + i], p1);
  }
  p0 = wred_sum(p0); p1 = wred_sum(p1);
  if (l == 0) { vn[row] = p0; vn2[row] = p1; }
}

// ---------- per-(b,t): attn softmax + q-dots (remv/addp/pgen) ----------
__global__ void k_attnscal(const float* __restrict__ logits, const float* __restrict__ q,
                           const float* __restrict__ Wr, const float* __restrict__ br,
                           const float* __restrict__ Wa, const float* __restrict__ ba,
                           const float* __restrict__ Wptr, const float* __restrict__ bptr,
                           float* __restrict__ attn_g, float* __restrict__ remv,
                           float* __restrict__ addp, float* __restrict__ pgen) {
  int row = blockIdx.x, l = threadIdx.x;           // 64 threads, BT blocks
  const float* src = logits + (size_t)row * S;
  float a = src[l];
  float b2 = (l + 64 < S) ? src[l + 64] : -INFINITY;
  float m = wred_max(fmaxf(a, b2));
  float ea = expf(a - m), eb = (l + 64 < S) ? expf(b2 - m) : 0.f;
  float inv = 1.f / wred_sum(ea + eb);
  attn_g[(size_t)row * S + l] = ea * inv;
  if (l + 64 < S) attn_g[(size_t)row * S + l + 64] = eb * inv;

  const float* qr = q + (size_t)row * D + l * 8;
  float pr = 0.f, pa = 0.f, pp = 0.f;
#pragma unroll
  for (int i = 0; i < 8; i++) {
    float x = qr[i];
    pr = fmaf(x, Wr[l * 8 + i], pr);
    pa = fmaf(x, Wa[l * 8 + i], pa);
    pp = fmaf(x, Wptr[l * 8 + i], pp);
  }
#pragma unroll
  for (int st = 32; st > 0; st >>= 1) {
    pr += __shfl_xor(pr, st, 64);
    pa += __shfl_xor(pa, st, 64);
    pp += __shfl_xor(pp, st, 64);
  }
  if (l == 0) {
    remv[row] = sigmoidf_(pr + br[0]);
    addp[row] = sigmoidf_(pa + ba[0]);
    pgen[row] = sigmoidf_(pp + bptr[0]);
  }
}

// ---------- per-(b,t): attnw window -> ra, ctxn ----------
__global__ __launch_bounds__(128) void k_attnw(const float* __restrict__ attn,
                                               const float* __restrict__ vn2,
                                               const float* __restrict__ remv,
                                               float* __restrict__ ra, float* __restrict__ ctxn) {
  int row = blockIdx.x, tid = threadIdx.x;         // 128 threads, BT blocks
  int b = row / T, t = row % T;
  __shared__ float red[128];
  int L = min(t + 1, WIN);
  float dnm = 0.f;
  for (int j = 0; j < L; j++) dnm += expf((float)(WIN - j) / 20.f);
  float p = 0.f;
  if (tid < S) {
    float aw = 0.f;
    for (int j = 0; j < L; j++)
      aw = fmaf(expf((float)(WIN - j) / 20.f) / dnm, attn[(size_t)(row - j) * S + tid], aw);
    ra[(size_t)row * S + tid] = remv[row] * aw;
    p = aw * vn2[b * S + tid];
  }
  red[tid] = p;
  __syncthreads();
  if (tid < 64) {
    float v2 = red[tid] + red[tid + 64];
    v2 = wred_sum(v2);
    if (tid == 0) ctxn[row] = v2;
  }
}

// ---------- fused prep: small conversions + qw window + Wqr/Wkr transposes ----------
constexpr int NB_CVT = 960;                        // (MP*D + D*D + FP*D)/4/256
constexpr int NB_QWB = MP + 64;                    // qw rows + selb pad rows
__global__ __launch_bounds__(256) void k_prep(
    const float* __restrict__ q, const float* __restrict__ Wq, const float* __restrict__ f,
    const float* __restrict__ Wqr, const float* __restrict__ Wkr,
    u16* __restrict__ qbf, u16* __restrict__ Wqlb, u16* __restrict__ fb,
    u16* __restrict__ qwb, u16* __restrict__ selb,
    u16* __restrict__ WqrT, u16* __restrict__ WkrT) {
  __shared__ float tile[64][65];
  int blk = blockIdx.x, tid = threadIdx.x;
  if (blk < NB_CVT) {
    int idx = blk * 256 + tid;
    constexpr int NQ = MP * D / 4;                 // 131072
    constexpr int NWQ = D * D / 4;                 // 65536
    if (idx < NQ) {
      int row = (idx * 4) / D;
      ushort4 o = {0, 0, 0, 0};
      if (row < BT) {
        float4 x = reinterpret_cast<const float4*>(q)[idx];
        o = {f2bf(x.x), f2bf(x.y), f2bf(x.z), f2bf(x.w)};
      }
      reinterpret_cast<ushort4*>(qbf)[idx] = o;
    } else if (idx < NQ + NWQ) {
      int j = idx - NQ;
      float4 x = reinterpret_cast<const float4*>(Wq)[j];
      ushort4 o = {f2bf(x.x), f2bf(x.y), f2bf(x.z), f2bf(x.w)};
      reinterpret_cast<ushort4*>(Wqlb)[j] = o;
    } else {
      int j = idx - NQ - NWQ;                      // 0 .. FP*D/4-1
      int row = (j * 4) / D;
      ushort4 o = {0, 0, 0, 0};
      if (row < B * R) {
        float4 x = reinterpret_cast<const float4*>(f)[j];
        o = {f2bf(x.x), f2bf(x.y), f2bf(x.z), f2bf(x.w)};
      }
      reinterpret_cast<ushort4*>(fb)[j] = o;
    }
  } else if (blk < NB_CVT + NB_QWB) {
    int row = blk - NB_CVT;
    if (row >= MP) {                               // zero selb pad rows
      size_t base = (size_t)BT * D + (size_t)(row - MP) * D;
      selb[base + tid] = 0; selb[base + tid + 256] = 0;
      return;
    }
    if (row >= BT) {
      qwb[(size_t)row * D + tid] = 0; qwb[(size_t)row * D + tid + 256] = 0;
      return;
    }
    int t = row % T, L = min(t + 1, WIN);
    float dnm = 0.f;
    for (int j = 0; j < L; j++) dnm += expf((float)(WIN - j) / 20.f);
    float a0 = 0.f, a1 = 0.f;
    for (int j = 0; j < L; j++) {
      float wj = expf((float)(WIN - j) / 20.f) / dnm;
      a0 = fmaf(wj, q[(size_t)(row - j) * D + tid], a0);
      a1 = fmaf(wj, q[(size_t)(row - j) * D + tid + 256], a1);
    }
    qwb[(size_t)row * D + tid] = f2bf(a0);
    qwb[(size_t)row * D + tid + 256] = f2bf(a1);
  } else {
    int qt = blk - NB_CVT - NB_QWB;                // 0..127
    const float* src = (qt < 64) ? Wqr : Wkr;
    u16* dst = (qt < 64) ? WqrT : WkrT;
    int q64 = qt & 63;
    int bx = q64 % 8, by = q64 / 8;
#pragma unroll
    for (int i = 0; i < 16; i++) {
      int e = i * 256 + tid, r = e >> 6, c = e & 63;
      tile[r][c] = src[(size_t)(by * 64 + r) * D + bx * 64 + c];
    }
    __syncthreads();
#pragma unroll
    for (int i = 0; i < 16; i++) {
      int e = i * 256 + tid, r = e >> 6, c = e & 63;
      dst[(size_t)(bx * 64 + r) * D + by * 64 + c] = f2bf(tile[c][r]);
    }
  }
}

// ---------- shared MFMA plumbing ----------
__device__ __forceinline__ void gload_lds16(const u16* g, u16* l) {
  __builtin_amdgcn_global_load_lds((const __attribute__((address_space(1))) void*)g,
                                   (__attribute__((address_space(3))) void*)l, 16, 0, 0);
}

// ---------- generic [Mpad x 512] @ [512 x 512]^T-rowmajor MFMA GEMM body ----------
__device__ __forceinline__ void gemm512_body(const u16* __restrict__ A, const u16* __restrict__ Bw,
                                             const float* __restrict__ bias, float* __restrict__ outp,
                                             int mlimit, int mt, int nt, int tid) {
  __shared__ u16 lds[2 * 128 * 64];
  u16* As = lds;
  u16* Bs = lds + 128 * 64;
  int m0 = mt * 128, n0 = nt * 128;
  int l = tid & 63;
  int w = tid >> 6, wm = w >> 1, wn = w & 1;
  f32x4 acc[4][4];
#pragma unroll
  for (int mb = 0; mb < 4; mb++)
#pragma unroll
    for (int nb = 0; nb < 4; nb++) acc[mb][nb] = (f32x4){0.f, 0.f, 0.f, 0.f};

  for (int k0 = 0; k0 < D; k0 += 64) {
#pragma unroll
    for (int i = 0; i < 4; i++) {
      int chunk = i * 256 + tid;
      int row = chunk >> 3, kc = chunk & 7;
      int kcs = kc ^ (row & 7);
      gload_lds16(A + (size_t)(m0 + row) * D + k0 + kcs * 8, As + chunk * 8);
      gload_lds16(Bw + (size_t)(n0 + row) * D + k0 + kcs * 8, Bs + chunk * 8);
    }
    __syncthreads();
#pragma unroll
    for (int kk = 0; kk < 2; kk++) {
      bf16x8 af[4], bfr[4];
#pragma unroll
      for (int mb = 0; mb < 4; mb++) {
        int row = wm * 64 + mb * 16 + (l & 15);
        int kc0 = kk * 4 + (l >> 4);
        af[mb] = *(const bf16x8*)(As + row * 64 + ((kc0 ^ (row & 7)) << 3));
      }
#pragma unroll
      for (int nb = 0; nb < 4; nb++) {
        int row = wn * 64 + nb * 16 + (l & 15);
        int kc0 = kk * 4 + (l >> 4);
        bfr[nb] = *(const bf16x8*)(Bs + row * 64 + ((kc0 ^ (row & 7)) << 3));
      }
#pragma unroll
      for (int mb = 0; mb < 4; mb++)
#pragma unroll
        for (int nb = 0; nb < 4; nb++)
          acc[mb][nb] = __builtin_amdgcn_mfma_f32_16x16x32_bf16(af[mb], bfr[nb], acc[mb][nb], 0, 0, 0);
    }
    __syncthreads();
  }

  float* ch = (float*)lds;
#pragma unroll
  for (int c = 0; c < 4; c++) {
    if (wm == (c >> 1)) {
#pragma unroll
      for (int nb = 0; nb < 4; nb++) {
        int col = wn * 64 + nb * 16 + (l & 15);
        float bl = bias ? bias[n0 + col] : 0.f;
#pragma unroll
        for (int mbi = 0; mbi < 2; mbi++) {
          int mb = (c & 1) * 2 + mbi;
#pragma unroll
          for (int q2 = 0; q2 < 4; q2++) {
            int row_local = mb * 16 + (l >> 4) * 4 + q2 - (c & 1) * 32;
            ch[row_local * 132 + col] = acc[mb][nb][q2] + bl;
          }
        }
      }
    }
    __syncthreads();
#pragma unroll
    for (int p = 0; p < 4; p++) {
      int r = p * 8 + (tid >> 5);
      int m = m0 + c * 32 + r;
      if (m < mlimit) {
        int seg = tid & 31;
        *(float4*)(outp + (size_t)m * D + n0 + seg * 4) =
            *(const float4*)(ch + r * 132 + seg * 4);
      }
    }
    __syncthreads();
  }
}

// dual dispatch: x<8 -> u = qwb@Wqlb ; x>=8 -> khf = fb@WkrT + bkr
__global__ __launch_bounds__(256) void k_gemm512_dual(
    const u16* __restrict__ qwb, const u16* __restrict__ Wqlb, float* __restrict__ u,
    const u16* __restrict__ fb, const u16* __restrict__ WkrT,
    const float* __restrict__ bkr, float* __restrict__ khf) {
  if (blockIdx.x < 8)
    gemm512_body(qwb, Wqlb, nullptr, u, BT, blockIdx.x, blockIdx.y, threadIdx.x);
  else
    gemm512_body(fb, WkrT, bkr, khf, B * R, blockIdx.x - 8, blockIdx.y, threadIdx.x);
}

__global__ __launch_bounds__(256) void k_gemm512(const u16* __restrict__ A, const u16* __restrict__ Bw,
                                                 const float* __restrict__ bias, float* __restrict__ outp,
                                                 int mlimit) {
  gemm512_body(A, Bw, bias, outp, mlimit, blockIdx.x, blockIdx.y, threadIdx.x);
}

// ---------- fused VU + beta/add_state chains ----------
__global__ __launch_bounds__(256) void k_vubeta(const float* __restrict__ u, const float* __restrict__ v,
                                                const float* __restrict__ attn, const float* __restrict__ ra,
                                                const float* __restrict__ addp, const float* __restrict__ ctxn,
                                                const float* __restrict__ vn, const float* __restrict__ bn,
                                                float* __restrict__ gammaT) {
  int bq = blockIdx.x;                             // b*5 + sc
  int b = bq / 5, sc = bq % 5;
  int tid = threadIdx.x;
  int tq = tid >> 2, sg = tid & 3;
  __shared__ float u_s[60][68];
  __shared__ float v_s[20][68];
  __shared__ float aw_s[60][20];
  __shared__ float ra_s[60][20];
  __shared__ float vu_s[60][20];
  __shared__ float gm_s[60][20];
  __shared__ float ap_s[T], cx_s[T], vns_s[20];
  for (int i = tid; i < T * 20; i += 256) {
    int t = i / 20, sl = i % 20;
    size_t base = ((size_t)b * T + t) * S + sc * 20 + sl;
    aw_s[t][sl] = attn[base];
    ra_s[t][sl] = ra[base];
  }
  if (tid < T) { ap_s[tid] = addp[b * T + tid]; cx_s[tid] = ctxn[b * T + tid]; }
  if (tid >= 64 && tid < 84) vns_s[tid - 64] = vn[b * S + sc * 20 + tid - 64];
  float acc[5] = {0, 0, 0, 0, 0};
  for (int kc = 0; kc < 8; kc++) {
    for (int i = tid; i < 60 * 64; i += 256) {
      int r = i >> 6, c = i & 63;
      u_s[r][c] = u[((size_t)b * T + r) * D + kc * 64 + c];
    }
    for (int i = tid; i < 20 * 64; i += 256) {
      int r = i >> 6, c = i & 63;
      v_s[r][c] = v[((size_t)b * S + sc * 20 + r) * D + kc * 64 + c];
    }
    __syncthreads();
    if (tq < 60) {
#pragma unroll
      for (int e0 = 0; e0 < 64; e0 += 4) {
        float4 uu = *(const float4*)&u_s[tq][e0];
#pragma unroll
        for (int m = 0; m < 5; m++) {
          float4 vv = *(const float4*)&v_s[sg * 5 + m][e0];
          acc[m] = fmaf(uu.x, vv.x, acc[m]);
          acc[m] = fmaf(uu.y, vv.y, acc[m]);
          acc[m] = fmaf(uu.z, vv.z, acc[m]);
          acc[m] = fmaf(uu.w, vv.w, acc[m]);
        }
      }
    }
    __syncthreads();
  }
  if (tq < 60) {
#pragma unroll
    for (int m = 0; m < 5; m++) vu_s[tq][sg * 5 + m] = acc[m];
  }
  __syncthreads();
  // fused add_state + beta chains (20 lanes, all data in LDS)
  if (tid < 20) {
    int s = sc * 20 + tid;
    float dec = (s < 50) ? 1.f - (float)(s + 1) / 50.f : 0.f;
    float a = dec, beta = dec;
    float vns = vns_s[tid], bnv = bn[0];
    for (int t = 0; t < T; t++) {
      float g = ap_s[t] * sigmoidf_(vns + cx_s[t] + bnv);
      float wv = (1.f - a) * g;
      a += wv;
      gm_s[t][tid] = aw_s[t][tid] * beta;          // gamma uses PRE-update beta
      beta = beta * (1.f - ra_s[t][tid] * sigmoidf_(beta * vu_s[t][tid])) + wv;
    }
  }
  __syncthreads();
  for (int i = tid; i < T * 20; i += 256) {
    int sl = i / 60, t = i % 60;
    gammaT[((size_t)b * S + sc * 20 + sl) * TP + t] = gm_s[t][sl];
  }
}

// ---------- sel (bf16) = gamma @ v per batch ----------
__global__ __launch_bounds__(512) void k_selgemm(const float* __restrict__ v,
                                                 const float* __restrict__ gammaT,
                                                 u16* __restrict__ selb) {
  int bq = blockIdx.x;
  int b = bq >> 2, dc = bq & 3;
  int tid = threadIdx.x;
  int dl = tid & 127, th = tid >> 7;
  int d = dc * 128 + dl;
  __shared__ float gT[S][TP];
  for (int i = tid; i < S * TP; i += 512) {
    int r = i >> 6, c = i & 63;
    gT[r][c] = gammaT[((size_t)b * S + r) * TP + c];
  }
  __syncthreads();
  float acc[16];
#pragma unroll
  for (int m = 0; m < 16; m++) acc[m] = 0.f;
  for (int ss = 0; ss < S; ss++) {
    float vv = v[((size_t)b * S + ss) * D + d];
    float4 g0 = *(const float4*)&gT[ss][th * 16];
    float4 g1 = *(const float4*)&gT[ss][th * 16 + 4];
    float4 g2 = *(const float4*)&gT[ss][th * 16 + 8];
    float4 g3 = *(const float4*)&gT[ss][th * 16 + 12];
    acc[0]  = fmaf(g0.x, vv, acc[0]);  acc[1]  = fmaf(g0.y, vv, acc[1]);
    acc[2]  = fmaf(g0.z, vv, acc[2]);  acc[3]  = fmaf(g0.w, vv, acc[3]);
    acc[4]  = fmaf(g1.x, vv, acc[4]);  acc[5]  = fmaf(g1.y, vv, acc[5]);
    acc[6]  = fmaf(g1.z, vv, acc[6]);  acc[7]  = fmaf(g1.w, vv, acc[7]);
    acc[8]  = fmaf(g2.x, vv, acc[8]);  acc[9]  = fmaf(g2.y, vv, acc[9]);
    acc[10] = fmaf(g2.z, vv, acc[10]); acc[11] = fmaf(g2.w, vv, acc[11]);
    acc[12] = fmaf(g3.x, vv, acc[12]); acc[13] = fmaf(g3.y, vv, acc[13]);
    acc[14] = fmaf(g3.z, vv, acc[14]); acc[15] = fmaf(g3.w, vv, acc[15]);
  }
#pragma unroll
  for (int m = 0; m < 16; m++) {
    int t = th * 16 + m;
    if (t < T) selb[((size_t)b * T + t) * D + d] = f2bf(acc[m]);
  }
}

// ---------- vocab GEMM: single-buffer 32KB LDS (4 blocks/CU), fused fp32->bf16 B convert.
// A: global_load_lds with pre-swizzled source (R4-proven). B: fp32 reg-stage ->
// cvt_pk -> swizzled ds_write (same involution). Next-step B loads issued AFTER the
// stage barrier so they hide under MFMA compute instead of extending the stage drain. ----------
__global__ __launch_bounds__(256) void k_gemm(const u16* __restrict__ A, const float* __restrict__ Bw,
                                              const float* __restrict__ blog, float* __restrict__ out) {
  __shared__ u16 lds[2 * 128 * 64];                // As | Bs, 32 KB
  u16* As = lds;
  u16* Bs = lds + 128 * 64;
  int bid = blockIdx.x;
  int swz = (bid & 7) * 250 + (bid >> 3);          // XCD-chunked bijective remap (2000 = 8*250)
  int m0 = (swz & 7) * 128, n0 = (swz >> 3) * 128;
  int tid = threadIdx.x, l = tid & 63;
  int w = tid >> 6, wm = w >> 1, wn = w & 1;

  f32x4 acc[4][4];
#pragma unroll
  for (int mb = 0; mb < 4; mb++)
#pragma unroll
    for (int nb = 0; nb < 4; nb++) acc[mb][nb] = (f32x4){0.f, 0.f, 0.f, 0.f};

  float breg[4][8];

#define ISSUE_B(k0)                                                                    \
  _Pragma("unroll")                                                                    \
  for (int i = 0; i < 4; i++) {                                                        \
    int chunk = i * 256 + tid, row = chunk >> 3, kc = chunk & 7;                       \
    const float* bsrc = Bw + (size_t)(n0 + row) * D + (k0) + kc * 8;                   \
    float4 x0 = *(const float4*)bsrc;                                                  \
    float4 x1 = *(const float4*)(bsrc + 4);                                            \
    breg[i][0] = x0.x; breg[i][1] = x0.y; breg[i][2] = x0.z; breg[i][3] = x0.w;        \
    breg[i][4] = x1.x; breg[i][5] = x1.y; breg[i][6] = x1.z; breg[i][7] = x1.w;        \
  }

#define WRITE_B()                                                                      \
  _Pragma("unroll")                                                                    \
  for (int i = 0; i < 4; i++) {                                                        \
    int chunk = i * 256 + tid, row = chunk >> 3, kc = chunk & 7;                       \
    int kcs = kc ^ (row & 7);                                                          \
    u32 p0 = cvtpk_bf16(breg[i][0], breg[i][1]);                                       \
    u32 p1 = cvtpk_bf16(breg[i][2], breg[i][3]);                                       \
    u32 p2 = cvtpk_bf16(breg[i][4], breg[i][5]);                                       \
    u32 p3 = cvtpk_bf16(breg[i][6], breg[i][7]);                                       \
    *(uint4*)&Bs[row * 64 + (kcs << 3)] = make_uint4(p0, p1, p2, p3);                  \
  }

#define ISSUE_A(k0)                                                                    \
  _Pragma("unroll")                                                                    \
  for (int i = 0; i < 4; i++) {                                                        \
    int chunk = i * 256 + tid, row = chunk >> 3, kc = chunk & 7;                       \
    int kcs = kc ^ (row & 7);                                                          \
    gload_lds16(A + (size_t)(m0 + row) * D + (k0) + kcs * 8, As + chunk * 8);          \
  }

  ISSUE_B(0)
  for (int kt = 0; kt < 8; kt++) {
    ISSUE_A(kt * 64)
    WRITE_B()                                      // waits this step's B (vmcnt), cvt, ds_write
    __syncthreads();                               // drains A dma + B writes: tile staged
    if (kt < 7) { ISSUE_B((kt + 1) * 64) }         // fp32 loads fly during compute
#pragma unroll
    for (int kk = 0; kk < 2; kk++) {
      bf16x8 af[4], bfr[4];
#pragma unroll
      for (int mb = 0; mb < 4; mb++) {
        int row = wm * 64 + mb * 16 + (l & 15);
        int kc0 = kk * 4 + (l >> 4);
        af[mb] = *(const bf16x8*)(As + row * 64 + ((kc0 ^ (row & 7)) << 3));
      }
#pragma unroll
      for (int nb = 0; nb < 4; nb++) {
        int row = wn * 64 + nb * 16 + (l & 15);
        int kc0 = kk * 4 + (l >> 4);
        bfr[nb] = *(const bf16x8*)(Bs + row * 64 + ((kc0 ^ (row & 7)) << 3));
      }
#pragma unroll
      for (int mb = 0; mb < 4; mb++)
#pragma unroll
        for (int nb = 0; nb < 4; nb++)
          acc[mb][nb] = __builtin_amdgcn_mfma_f32_16x16x32_bf16(af[mb], bfr[nb], acc[mb][nb], 0, 0, 0);
    }
    __syncthreads();                               // all reads done: LDS free for next stage
  }
#undef ISSUE_B
#undef WRITE_B
#undef ISSUE_A

  // coalesced epilogue: 32x128 f32 chunks via LDS, 512B-contiguous stores
  float* ch = (float*)lds;                         // 16.9 KB, spans As|Bs (contiguous)
#pragma unroll
  for (int c = 0; c < 4; c++) {
    if (wm == (c >> 1)) {
#pragma unroll
      for (int nb = 0; nb < 4; nb++) {
        int col = wn * 64 + nb * 16 + (l & 15);
        float bl = blog[n0 + col];
#pragma unroll
        for (int mbi = 0; mbi < 2; mbi++) {
          int mb = (c & 1) * 2 + mbi;
#pragma unroll
          for (int q2 = 0; q2 < 4; q2++) {
            int row_local = mb * 16 + (l >> 4) * 4 + q2 - (c & 1) * 32;
            ch[row_local * 132 + col] = acc[mb][nb][q2] + bl;
          }
        }
      }
    }
    __syncthreads();
#pragma unroll
    for (int p = 0; p < 4; p++) {
      int r = p * 8 + (tid >> 5);
      int m = m0 + c * 32 + r;
      if (m < BT) {
        int seg = tid & 31;
        *(float4*)(out + (size_t)m * VR + n0 + seg * 4) =
            *(const float4*)(ch + r * 132 + seg * 4);
      }
    }
    __syncthreads();
  }
}

// ---------- role scores -> softmax(mean over heads) * p_gen -> out[:, V:] ----------
__global__ void k_role(const float* __restrict__ khf, const float* __restrict__ qh,
                       const float* __restrict__ pgen, float* __restrict__ out) {
  int row = blockIdx.x, tid = threadIdx.x;         // 192 threads
  int b = row / T;
  __shared__ float sc[H * R];
  __shared__ float pr[H * R];
  if (tid < H * R) {
    int h = tid / R, r = tid % R;
    const float* qp = qh + (size_t)row * D + h * DK;
    const float* kp = khf + (size_t)(b * R + r) * D + h * DK;
    float acc = 0.f;
#pragma unroll
    for (int i = 0; i < DK; i++) acc = fmaf(qp[i], kp[i], acc);
    sc[tid] = acc * 0.125f;                        // 1/sqrt(64)
  }
  __syncthreads();
  if (tid < H) {
    float m = -INFINITY;
    for (int r = 0; r < R; r++) m = fmaxf(m, sc[tid * R + r]);
    float ssum = 0.f;
    for (int r = 0; r < R; r++) { float e = expf(sc[tid * R + r] - m); pr[tid * R + r] = e; ssum += e; }
    float inv = 1.f / ssum;
    for (int r = 0; r < R; r++) pr[tid * R + r] *= inv;
  }
  __syncthreads();
  if (tid < R) {
    float acc = 0.f;
#pragma unroll
    for (int h = 0; h < H; h++) acc += pr[h * R + tid];
    out[(size_t)row * VR + V + tid] = acc * (1.f / H) * pgen[row];
  }
}

extern "C" void kernel_launch(void* const* d_in, const int* in_sizes, int n_in,
                              void* d_out, int out_size, void* d_ws, size_t ws_size,
                              hipStream_t stream) {
  const float* v_out  = (const float*)d_in[0];
  const float* f_out  = (const float*)d_in[1];
  const float* q_seq  = (const float*)d_in[2];
  const float* logits = (const float*)d_in[3];
  const float* Wr     = (const float*)d_in[4];
  const float* br     = (const float*)d_in[5];
  const float* Wa     = (const float*)d_in[6];
  const float* ba     = (const float*)d_in[7];
  const float* Wq_lin = (const float*)d_in[8];
  const float* Wn     = (const float*)d_in[9];
  const float* bn     = (const float*)d_in[10];
  const float* Wlogit = (const float*)d_in[11];
  const float* blogit = (const float*)d_in[12];
  const float* Wptr   = (const float*)d_in[13];
  const float* bptr   = (const float*)d_in[14];
  const float* Wqr    = (const float*)d_in[15];
  const float* bqr    = (const float*)d_in[16];
  const float* Wkr    = (const float*)d_in[17];
  const float* bkr    = (const float*)d_in[18];
  float* out = (float*)d_out;
  float* ws  = (float*)d_ws;

  float* attn   = ws;                                  // BT*S
  float* ra     = attn   + (size_t)BT * S;             // BT*S
  float* u      = ra     + (size_t)BT * S;             // BT*D
  float* pgen   = u      + (size_t)BT * D;             // BT
  float* remv   = pgen   + BT;                         // BT
  float* addp   = remv   + BT;                         // BT
  float* ctxn   = addp   + BT;                         // BT
  float* vn     = ctxn   + BT;                         // B*S
  float* vn2    = vn     + B * S;                      // B*S
  float* khf    = vn2    + B * S;                      // B*R*D
  float* qh     = khf    + (size_t)B * R * D;          // BT*D
  float* gammaT = qh     + (size_t)BT * D;             // B*S*TP
  u16*   qwb    = (u16*)(gammaT + (size_t)B * S * TP); // MP*D
  u16*   selb   = qwb  + (size_t)MP * D;               // MP*D
  u16*   fb     = selb + (size_t)MP * D;               // FP*D
  u16*   Wqlb   = fb   + (size_t)FP * D;               // D*D
  u16*   WqrT   = Wqlb + (size_t)D * D;                // D*D
  u16*   WkrT   = WqrT + (size_t)D * D;                // D*D
  u16*   qbf    = WkrT + (size_t)D * D;                // MP*D

  // flat, massively-parallel precompute
  k_vn      <<<B * S,     64, 0, stream>>>(v_out, Wn, vn, vn2);
  k_attnscal<<<BT,        64, 0, stream>>>(logits, q_seq, Wr, br, Wa, ba, Wptr, bptr,
                                           attn, remv, addp, pgen);
  k_attnw   <<<BT,       128, 0, stream>>>(attn, vn2, remv, ra, ctxn);
  k_prep    <<<NB_CVT + NB_QWB + 128, 256, 0, stream>>>(
      q_seq, Wq_lin, f_out, Wqr, Wkr, qbf, Wqlb, fb, qwb, selb, WqrT, WkrT);

  // u = qw @ Wq_lin^T  and  khf = f @ Wkr + bkr  (one dual MFMA launch)
  k_gemm512_dual<<<dim3(8 + FP / 128, 4), 256, 0, stream>>>(qwb, Wqlb, u, fb, WkrT, bkr, khf);
  // rank-1 recurrence: VU + fused add_state/beta chains
  k_vubeta <<<B * 5,      256, 0, stream>>>(u, v_out, attn, ra, addp, ctxn, vn, bn, gammaT);
  k_selgemm<<<B * 4,      512, 0, stream>>>(v_out, gammaT, selb);
  // qh = sel @ Wqr + bqr  (MFMA)
  k_gemm512<<<dim3(MP / 128, 4), 256, 0, stream>>>(selb, WqrT, bqr, qh, BT);

  // vocab GEMM (bulk of FLOPs) — reads Wlogit fp32 directly, converts in-kernel
  k_gemm   <<<(MP / 128) * (V / 128), 256, 0, stream>>>(qbf, Wlogit, blogit, out);

  // role epilogue
  k_role   <<<BT,        192, 0, stream>>>(khf, qh, pgen, out);
}

// Round 12
// 214.148 us; speedup vs baseline: 1.0369x; 1.0369x over previous
//
#include <hip/hip_runtime.h>
#include <math.h>

// Problem constants
constexpr int B = 16, S = 100, T = 60, D = 512, H = 8, V = 32000, R = 20;
constexpr int DK = 64, WIN = 20;
constexpr int VR = V + R;        // 32020
constexpr int BT = B * T;        // 960
constexpr int MP = 1024;         // padded GEMM M
constexpr int TP = 64;           // padded T for gammaT rows
constexpr int FP = 384;          // padded B*R rows for kh GEMM

typedef unsigned short u16;
typedef __attribute__((ext_vector_type(8))) short bf16x8;
typedef __attribute__((ext_vector_type(4))) float f32x4;

__device__ __forceinline__ float wred_sum(float v) {
#pragma unroll
  for (int st = 32; st > 0; st >>= 1) v += __shfl_xor(v, st, 64);
  return v;
}
__device__ __forceinline__ float wred_max(float v) {
#pragma unroll
  for (int st = 32; st > 0; st >>= 1) v = fmaxf(v, __shfl_xor(v, st, 64));
  return v;
}
__device__ __forceinline__ float sigmoidf_(float x) { return 1.f / (1.f + expf(-x)); }
__device__ __forceinline__ u16 f2bf(float x) {
  unsigned u = __float_as_uint(x);
  return (u16)((u + 0x7fffu + ((u >> 16) & 1u)) >> 16);
}
__device__ __forceinline__ void gload_lds16(const u16* g, u16* l) {
  __builtin_amdgcn_global_load_lds((const __attribute__((address_space(1))) void*)g,
                                   (__attribute__((address_space(3))) void*)l, 16, 0, 0);
}

// ================= bodies (proven code, parameterized dispatch) =================

// ---- vn/vn2 per (b,s); one wave per row ----
__device__ __forceinline__ void vn_body(int row, int l, const float* __restrict__ v,
                                        const float* __restrict__ Wn,
                                        float* __restrict__ vn, float* __restrict__ vn2) {
  const float* vr = v + (size_t)row * D + l * 8;
  float p0 = 0.f, p1 = 0.f;
#pragma unroll
  for (int i = 0; i < 8; i++) {
    float x = vr[i];
    p0 = fmaf(x, Wn[l * 8 + i], p0);
    p1 = fmaf(x, Wn[D + l * 8 + i], p1);
  }
  p0 = wred_sum(p0); p1 = wred_sum(p1);
  if (l == 0) { vn[row] = p0; vn2[row] = p1; }
}

// ---- attn softmax + q-dots per (b,t); one wave per row ----
__device__ __forceinline__ void attnscal_body(int row, int l,
    const float* __restrict__ logits, const float* __restrict__ q,
    const float* __restrict__ Wr, const float* __restrict__ br,
    const float* __restrict__ Wa, const float* __restrict__ ba,
    const float* __restrict__ Wptr, const float* __restrict__ bptr,
    float* __restrict__ attn_g, float* __restrict__ remv,
    float* __restrict__ addp, float* __restrict__ pgen) {
  const float* src = logits + (size_t)row * S;
  float a = src[l];
  float b2 = (l + 64 < S) ? src[l + 64] : -INFINITY;
  float m = wred_max(fmaxf(a, b2));
  float ea = expf(a - m), eb = (l + 64 < S) ? expf(b2 - m) : 0.f;
  float inv = 1.f / wred_sum(ea + eb);
  attn_g[(size_t)row * S + l] = ea * inv;
  if (l + 64 < S) attn_g[(size_t)row * S + l + 64] = eb * inv;

  const float* qr = q + (size_t)row * D + l * 8;
  float pr = 0.f, pa = 0.f, pp = 0.f;
#pragma unroll
  for (int i = 0; i < 8; i++) {
    float x = qr[i];
    pr = fmaf(x, Wr[l * 8 + i], pr);
    pa = fmaf(x, Wa[l * 8 + i], pa);
    pp = fmaf(x, Wptr[l * 8 + i], pp);
  }
#pragma unroll
  for (int st = 32; st > 0; st >>= 1) {
    pr += __shfl_xor(pr, st, 64);
    pa += __shfl_xor(pa, st, 64);
    pp += __shfl_xor(pp, st, 64);
  }
  if (l == 0) {
    remv[row] = sigmoidf_(pr + br[0]);
    addp[row] = sigmoidf_(pa + ba[0]);
    pgen[row] = sigmoidf_(pp + bptr[0]);
  }
}

// ---- attnw window -> ra, ctxn per (b,t); 256-thread safe (upper half barrier-only) ----
__device__ __forceinline__ void attnw_body(int row, int tid, float* red,
    const float* __restrict__ attn, const float* __restrict__ vn2,
    const float* __restrict__ remv, float* __restrict__ ra, float* __restrict__ ctxn) {
  int b = row / T, t = row % T;
  int L = min(t + 1, WIN);
  if (tid < 128) {
    float dnm = 0.f;
    for (int j = 0; j < L; j++) dnm += expf((float)(WIN - j) / 20.f);
    float p = 0.f;
    if (tid < S) {
      float aw = 0.f;
      for (int j = 0; j < L; j++)
        aw = fmaf(expf((float)(WIN - j) / 20.f) / dnm, attn[(size_t)(row - j) * S + tid], aw);
      ra[(size_t)row * S + tid] = remv[row] * aw;
      p = aw * vn2[b * S + tid];
    }
    red[tid] = p;
  }
  __syncthreads();
  if (tid < 64) {
    float v2 = red[tid] + red[tid + 64];
    v2 = wred_sum(v2);
    if (tid == 0) ctxn[row] = v2;
  }
}

// ---- prep (conversions incl Wlogit, qw window, weight transposes) ----
constexpr int NB_CVT = 16960;                      // (V*D + MP*D + D*D + FP*D)/4/256
constexpr int NB_QWB = MP + 64;
constexpr int NB_PREP = NB_CVT + NB_QWB + 128;     // 18176
__device__ __forceinline__ void prep_body(int blk, int tid, float (*tile)[65],
    const float* __restrict__ Wlogit, const float* __restrict__ q,
    const float* __restrict__ Wq, const float* __restrict__ f,
    const float* __restrict__ Wqr, const float* __restrict__ Wkr,
    u16* __restrict__ Wlbf, u16* __restrict__ qbf,
    u16* __restrict__ Wqlb, u16* __restrict__ fb,
    u16* __restrict__ qwb, u16* __restrict__ selb,
    u16* __restrict__ WqrT, u16* __restrict__ WkrT) {
  if (blk < NB_CVT) {
    int idx = blk * 256 + tid;
    constexpr int NW = V * D / 4;
    constexpr int NQ = MP * D / 4;
    constexpr int NWQ = D * D / 4;
    if (idx < NW) {
      float4 x = reinterpret_cast<const float4*>(Wlogit)[idx];
      ushort4 o = {f2bf(x.x), f2bf(x.y), f2bf(x.z), f2bf(x.w)};
      reinterpret_cast<ushort4*>(Wlbf)[idx] = o;
    } else if (idx < NW + NQ) {
      int j = idx - NW;
      int row = (j * 4) / D;
      ushort4 o = {0, 0, 0, 0};
      if (row < BT) {
        float4 x = reinterpret_cast<const float4*>(q)[j];
        o = {f2bf(x.x), f2bf(x.y), f2bf(x.z), f2bf(x.w)};
      }
      reinterpret_cast<ushort4*>(qbf)[j] = o;
    } else if (idx < NW + NQ + NWQ) {
      int j = idx - NW - NQ;
      float4 x = reinterpret_cast<const float4*>(Wq)[j];
      ushort4 o = {f2bf(x.x), f2bf(x.y), f2bf(x.z), f2bf(x.w)};
      reinterpret_cast<ushort4*>(Wqlb)[j] = o;
    } else {
      int j = idx - NW - NQ - NWQ;
      int row = (j * 4) / D;
      ushort4 o = {0, 0, 0, 0};
      if (row < B * R) {
        float4 x = reinterpret_cast<const float4*>(f)[j];
        o = {f2bf(x.x), f2bf(x.y), f2bf(x.z), f2bf(x.w)};
      }
      reinterpret_cast<ushort4*>(fb)[j] = o;
    }
  } else if (blk < NB_CVT + NB_QWB) {
    int row = blk - NB_CVT;
    if (row >= MP) {                               // zero selb pad rows
      size_t base = (size_t)BT * D + (size_t)(row - MP) * D;
      selb[base + tid] = 0; selb[base + tid + 256] = 0;
      return;
    }
    if (row >= BT) {
      qwb[(size_t)row * D + tid] = 0; qwb[(size_t)row * D + tid + 256] = 0;
      return;
    }
    int t = row % T, L = min(t + 1, WIN);
    float dnm = 0.f;
    for (int j = 0; j < L; j++) dnm += expf((float)(WIN - j) / 20.f);
    float a0 = 0.f, a1 = 0.f;
    for (int j = 0; j < L; j++) {
      float wj = expf((float)(WIN - j) / 20.f) / dnm;
      a0 = fmaf(wj, q[(size_t)(row - j) * D + tid], a0);
      a1 = fmaf(wj, q[(size_t)(row - j) * D + tid + 256], a1);
    }
    qwb[(size_t)row * D + tid] = f2bf(a0);
    qwb[(size_t)row * D + tid + 256] = f2bf(a1);
  } else {
    int qt = blk - NB_CVT - NB_QWB;                // 0..127
    const float* src = (qt < 64) ? Wqr : Wkr;
    u16* dst = (qt < 64) ? WqrT : WkrT;
    int q64 = qt & 63;
    int bx = q64 % 8, by = q64 / 8;
#pragma unroll
    for (int i = 0; i < 16; i++) {
      int e = i * 256 + tid, r = e >> 6, c = e & 63;
      tile[r][c] = src[(size_t)(by * 64 + r) * D + bx * 64 + c];
    }
    __syncthreads();
#pragma unroll
    for (int i = 0; i < 16; i++) {
      int e = i * 256 + tid, r = e >> 6, c = e & 63;
      dst[(size_t)(bx * 64 + r) * D + by * 64 + c] = f2bf(tile[c][r]);
    }
  }
}

// ---- generic [Mpad x 512] @ [512 x 512]^T MFMA GEMM (R4-proven loop) ----
__device__ __forceinline__ void gemm512_body(const u16* __restrict__ A, const u16* __restrict__ Bw,
                                             const float* __restrict__ bias, float* __restrict__ outp,
                                             int mlimit, int mt, int nt, int tid, u16* ldsbuf) {
  u16* As = ldsbuf;
  u16* Bs = ldsbuf + 128 * 64;
  int m0 = mt * 128, n0 = nt * 128;
  int l = tid & 63;
  int w = tid >> 6, wm = w >> 1, wn = w & 1;
  f32x4 acc[4][4];
#pragma unroll
  for (int mb = 0; mb < 4; mb++)
#pragma unroll
    for (int nb = 0; nb < 4; nb++) acc[mb][nb] = (f32x4){0.f, 0.f, 0.f, 0.f};

  for (int k0 = 0; k0 < D; k0 += 64) {
#pragma unroll
    for (int i = 0; i < 4; i++) {
      int chunk = i * 256 + tid;
      int row = chunk >> 3, kc = chunk & 7;
      int kcs = kc ^ (row & 7);
      gload_lds16(A + (size_t)(m0 + row) * D + k0 + kcs * 8, As + chunk * 8);
      gload_lds16(Bw + (size_t)(n0 + row) * D + k0 + kcs * 8, Bs + chunk * 8);
    }
    __syncthreads();
#pragma unroll
    for (int kk = 0; kk < 2; kk++) {
      bf16x8 af[4], bfr[4];
#pragma unroll
      for (int mb = 0; mb < 4; mb++) {
        int row = wm * 64 + mb * 16 + (l & 15);
        int kc0 = kk * 4 + (l >> 4);
        af[mb] = *(const bf16x8*)(As + row * 64 + ((kc0 ^ (row & 7)) << 3));
      }
#pragma unroll
      for (int nb = 0; nb < 4; nb++) {
        int row = wn * 64 + nb * 16 + (l & 15);
        int kc0 = kk * 4 + (l >> 4);
        bfr[nb] = *(const bf16x8*)(Bs + row * 64 + ((kc0 ^ (row & 7)) << 3));
      }
#pragma unroll
      for (int mb = 0; mb < 4; mb++)
#pragma unroll
        for (int nb = 0; nb < 4; nb++)
          acc[mb][nb] = __builtin_amdgcn_mfma_f32_16x16x32_bf16(af[mb], bfr[nb], acc[mb][nb], 0, 0, 0);
    }
    __syncthreads();
  }

  float* ch = (float*)ldsbuf;
#pragma unroll
  for (int c = 0; c < 4; c++) {
    if (wm == (c >> 1)) {
#pragma unroll
      for (int nb = 0; nb < 4; nb++) {
        int col = wn * 64 + nb * 16 + (l & 15);
        float bl = bias ? bias[n0 + col] : 0.f;
#pragma unroll
        for (int mbi = 0; mbi < 2; mbi++) {
          int mb = (c & 1) * 2 + mbi;
#pragma unroll
          for (int q2 = 0; q2 < 4; q2++) {
            int row_local = mb * 16 + (l >> 4) * 4 + q2 - (c & 1) * 32;
            ch[row_local * 132 + col] = acc[mb][nb][q2] + bl;
          }
        }
      }
    }
    __syncthreads();
#pragma unroll
    for (int p = 0; p < 4; p++) {
      int r = p * 8 + (tid >> 5);
      int m = m0 + c * 32 + r;
      if (m < mlimit) {
        int seg = tid & 31;
        *(float4*)(outp + (size_t)m * D + n0 + seg * 4) =
            *(const float4*)(ch + r * 132 + seg * 4);
      }
    }
    __syncthreads();
  }
}

// ---- vocab GEMM block (R4/R9-proven all-bf16, XCD remap, coalesced epilogue) ----
__device__ __forceinline__ void vocab_body(int bid, int tid, u16* ldsbuf,
    const u16* __restrict__ A, const u16* __restrict__ Bw,
    const float* __restrict__ blog, float* __restrict__ out) {
  u16* As = ldsbuf;
  u16* Bs = ldsbuf + 128 * 64;
  int swz = (bid & 7) * 250 + (bid >> 3);          // bijective on [0,2000)
  int m0 = (swz & 7) * 128, n0 = (swz >> 3) * 128;
  int l = tid & 63;
  int w = tid >> 6, wm = w >> 1, wn = w & 1;

  f32x4 acc[4][4];
#pragma unroll
  for (int mb = 0; mb < 4; mb++)
#pragma unroll
    for (int nb = 0; nb < 4; nb++) acc[mb][nb] = (f32x4){0.f, 0.f, 0.f, 0.f};

  for (int k0 = 0; k0 < D; k0 += 64) {
#pragma unroll
    for (int i = 0; i < 4; i++) {
      int chunk = i * 256 + tid;
      int row = chunk >> 3, kc = chunk & 7;
      int kcs = kc ^ (row & 7);
      gload_lds16(A + (size_t)(m0 + row) * D + k0 + kcs * 8, As + chunk * 8);
      gload_lds16(Bw + (size_t)(n0 + row) * D + k0 + kcs * 8, Bs + chunk * 8);
    }
    __syncthreads();
#pragma unroll
    for (int kk = 0; kk < 2; kk++) {
      bf16x8 af[4], bfr[4];
#pragma unroll
      for (int mb = 0; mb < 4; mb++) {
        int row = wm * 64 + mb * 16 + (l & 15);
        int kc0 = kk * 4 + (l >> 4);
        af[mb] = *(const bf16x8*)(As + row * 64 + ((kc0 ^ (row & 7)) << 3));
      }
#pragma unroll
      for (int nb = 0; nb < 4; nb++) {
        int row = wn * 64 + nb * 16 + (l & 15);
        int kc0 = kk * 4 + (l >> 4);
        bfr[nb] = *(const bf16x8*)(Bs + row * 64 + ((kc0 ^ (row & 7)) << 3));
      }
#pragma unroll
      for (int mb = 0; mb < 4; mb++)
#pragma unroll
        for (int nb = 0; nb < 4; nb++)
          acc[mb][nb] = __builtin_amdgcn_mfma_f32_16x16x32_bf16(af[mb], bfr[nb], acc[mb][nb], 0, 0, 0);
    }
    __syncthreads();
  }

  float* ch = (float*)ldsbuf;
#pragma unroll
  for (int c = 0; c < 4; c++) {
    if (wm == (c >> 1)) {
#pragma unroll
      for (int nb = 0; nb < 4; nb++) {
        int col = wn * 64 + nb * 16 + (l & 15);
        float bl = blog[n0 + col];
#pragma unroll
        for (int mbi = 0; mbi < 2; mbi++) {
          int mb = (c & 1) * 2 + mbi;
#pragma unroll
          for (int q2 = 0; q2 < 4; q2++) {
            int row_local = mb * 16 + (l >> 4) * 4 + q2 - (c & 1) * 32;
            ch[row_local * 132 + col] = acc[mb][nb][q2] + bl;
          }
        }
      }
    }
    __syncthreads();
#pragma unroll
    for (int p = 0; p < 4; p++) {
      int r = p * 8 + (tid >> 5);
      int m = m0 + c * 32 + r;
      if (m < BT) {
        int seg = tid & 31;
        *(float4*)(out + (size_t)m * VR + n0 + seg * 4) =
            *(const float4*)(ch + r * 132 + seg * 4);
      }
    }
    __syncthreads();
  }
}

// ---- selgemm at 256 threads: each thread covers 2 t-groups ----
__device__ __forceinline__ void selgemm_body(int bq, int tid, float* gT /*[S][TP]*/,
    const float* __restrict__ v, const float* __restrict__ gammaT, u16* __restrict__ selb) {
  int b = bq >> 2, dc = bq & 3;
  int dl = tid & 127, th0 = tid >> 7;              // 0..1
  int d = dc * 128 + dl;
  for (int i = tid; i < S * TP; i += 256) {
    int r = i >> 6, c = i & 63;
    gT[r * TP + c] = gammaT[((size_t)b * S + r) * TP + c];
  }
  __syncthreads();
  float acc[2][16];
#pragma unroll
  for (int g = 0; g < 2; g++)
#pragma unroll
    for (int m = 0; m < 16; m++) acc[g][m] = 0.f;
  for (int ss = 0; ss < S; ss++) {
    float vv = v[((size_t)b * S + ss) * D + d];
#pragma unroll
    for (int g = 0; g < 2; g++) {
      int tg = th0 + 2 * g;
      const float* gp = gT + ss * TP + tg * 16;
      float4 g0 = *(const float4*)gp;
      float4 g1 = *(const float4*)(gp + 4);
      float4 g2 = *(const float4*)(gp + 8);
      float4 g3 = *(const float4*)(gp + 12);
      acc[g][0]  = fmaf(g0.x, vv, acc[g][0]);  acc[g][1]  = fmaf(g0.y, vv, acc[g][1]);
      acc[g][2]  = fmaf(g0.z, vv, acc[g][2]);  acc[g][3]  = fmaf(g0.w, vv, acc[g][3]);
      acc[g][4]  = fmaf(g1.x, vv, acc[g][4]);  acc[g][5]  = fmaf(g1.y, vv, acc[g][5]);
      acc[g][6]  = fmaf(g1.z, vv, acc[g][6]);  acc[g][7]  = fmaf(g1.w, vv, acc[g][7]);
      acc[g][8]  = fmaf(g2.x, vv, acc[g][8]);  acc[g][9]  = fmaf(g2.y, vv, acc[g][9]);
      acc[g][10] = fmaf(g2.z, vv, acc[g][10]); acc[g][11] = fmaf(g2.w, vv, acc[g][11]);
      acc[g][12] = fmaf(g3.x, vv, acc[g][12]); acc[g][13] = fmaf(g3.y, vv, acc[g][13]);
      acc[g][14] = fmaf(g3.z, vv, acc[g][14]); acc[g][15] = fmaf(g3.w, vv, acc[g][15]);
    }
  }
#pragma unroll
  for (int g = 0; g < 2; g++) {
    int tg = th0 + 2 * g;
#pragma unroll
    for (int m = 0; m < 16; m++) {
      int t = tg * 16 + m;
      if (t < T) selb[((size_t)b * T + t) * D + d] = f2bf(acc[g][m]);
    }
  }
}

// ================= dispatch kernels =================

// combo1: prep (incl Wlogit cvt) + vn + attnscal — all input-only
__global__ __launch_bounds__(256) void k_combo1(
    const float* Wlogit, const float* q, const float* Wq, const float* f,
    const float* Wqr, const float* Wkr, const float* logits, const float* v,
    const float* Wn, const float* Wr, const float* br, const float* Wa, const float* ba,
    const float* Wptr, const float* bptr,
    u16* Wlbf, u16* qbf, u16* Wqlb, u16* fb, u16* qwb, u16* selb, u16* WqrT, u16* WkrT,
    float* vn, float* vn2, float* attn_g, float* remv, float* addp, float* pgen) {
  __shared__ float tile[64][65];
  int blk = blockIdx.x, tid = threadIdx.x;
  if (blk < NB_PREP) {
    prep_body(blk, tid, tile, Wlogit, q, Wq, f, Wqr, Wkr,
              Wlbf, qbf, Wqlb, fb, qwb, selb, WqrT, WkrT);
  } else if (blk < NB_PREP + 400) {
    int row = (blk - NB_PREP) * 4 + (tid >> 6);    // 1600 rows
    vn_body(row, tid & 63, v, Wn, vn, vn2);
  } else {
    int row = (blk - NB_PREP - 400) * 4 + (tid >> 6);  // 960 rows
    attnscal_body(row, tid & 63, logits, q, Wr, br, Wa, ba, Wptr, bptr,
                  attn_g, remv, addp, pgen);
  }
}

// combo2: vocab chunk0 [0,667) + gemm512 dual (44) + attnw (960)
__global__ __launch_bounds__(256) void k_combo2(
    const u16* qbf, const u16* Wlbf, const float* blog, float* out,
    const u16* qwb, const u16* Wqlb, float* u,
    const u16* fb, const u16* WkrT, const float* bkr, float* khf,
    const float* attn, const float* vn2, const float* remv, float* ra, float* ctxn) {
  __shared__ u16 lds[2 * 128 * 64];
  int blk = blockIdx.x, tid = threadIdx.x;
  if (blk < 667) {
    vocab_body(blk, tid, lds, qbf, Wlbf, blog, out);
  } else if (blk < 711) {
    int z = blk - 667, xx = z % 11, yy = z / 11;
    if (xx < 8) gemm512_body(qwb, Wqlb, nullptr, u, BT, xx, yy, tid, lds);
    else        gemm512_body(fb, WkrT, bkr, khf, B * R, xx - 8, yy, tid, lds);
  } else {
    attnw_body(blk - 711, tid, (float*)lds, attn, vn2, remv, ra, ctxn);
  }
}

// combo3: vocab chunk1 [667,1334) + selgemm (64)
__global__ __launch_bounds__(256) void k_combo3(
    const u16* qbf, const u16* Wlbf, const float* blog, float* out,
    const float* v, const float* gammaT, u16* selb) {
  __shared__ u16 lds[2 * 128 * 64];
  int blk = blockIdx.x, tid = threadIdx.x;
  if (blk < 667) vocab_body(667 + blk, tid, lds, qbf, Wlbf, blog, out);
  else           selgemm_body(blk - 667, tid, (float*)lds, v, gammaT, selb);
}

// combo4: vocab chunk2 [1334,2000) + qh gemm512 (32)
__global__ __launch_bounds__(256) void k_combo4(
    const u16* qbf, const u16* Wlbf, const float* blog, float* out,
    const u16* selb, const u16* WqrT, const float* bqr, float* qh) {
  __shared__ u16 lds[2 * 128 * 64];
  int blk = blockIdx.x, tid = threadIdx.x;
  if (blk < 666) vocab_body(1334 + blk, tid, lds, qbf, Wlbf, blog, out);
  else {
    int z = blk - 666;
    gemm512_body(selb, WqrT, bqr, qh, BT, z % 8, z / 8, tid, lds);
  }
}

// ---------- fused VU + beta/add_state chains (unchanged) ----------
__global__ __launch_bounds__(256) void k_vubeta(const float* __restrict__ u, const float* __restrict__ v,
                                                const float* __restrict__ attn, const float* __restrict__ ra,
                                                const float* __restrict__ addp, const float* __restrict__ ctxn,
                                                const float* __restrict__ vn, const float* __restrict__ bn,
                                                float* __restrict__ gammaT) {
  int bq = blockIdx.x;                             // b*5 + sc
  int b = bq / 5, sc = bq % 5;
  int tid = threadIdx.x;
  int tq = tid >> 2, sg = tid & 3;
  __shared__ float u_s[60][68];
  __shared__ float v_s[20][68];
  __shared__ float aw_s[60][20];
  __shared__ float ra_s[60][20];
  __shared__ float vu_s[60][20];
  __shared__ float gm_s[60][20];
  __shared__ float ap_s[T], cx_s[T], vns_s[20];
  for (int i = tid; i < T * 20; i += 256) {
    int t = i / 20, sl = i % 20;
    size_t base = ((size_t)b * T + t) * S + sc * 20 + sl;
    aw_s[t][sl] = attn[base];
    ra_s[t][sl] = ra[base];
  }
  if (tid < T) { ap_s[tid] = addp[b * T + tid]; cx_s[tid] = ctxn[b * T + tid]; }
  if (tid >= 64 && tid < 84) vns_s[tid - 64] = vn[b * S + sc * 20 + tid - 64];
  float acc[5] = {0, 0, 0, 0, 0};
  for (int kc = 0; kc < 8; kc++) {
    for (int i = tid; i < 60 * 64; i += 256) {
      int r = i >> 6, c = i & 63;
      u_s[r][c] = u[((size_t)b * T + r) * D + kc * 64 + c];
    }
    for (int i = tid; i < 20 * 64; i += 256) {
      int r = i >> 6, c = i & 63;
      v_s[r][c] = v[((size_t)b * S + sc * 20 + r) * D + kc * 64 + c];
    }
    __syncthreads();
    if (tq < 60) {
#pragma unroll
      for (int e0 = 0; e0 < 64; e0 += 4) {
        float4 uu = *(const float4*)&u_s[tq][e0];
#pragma unroll
        for (int m = 0; m < 5; m++) {
          float4 vv = *(const float4*)&v_s[sg * 5 + m][e0];
          acc[m] = fmaf(uu.x, vv.x, acc[m]);
          acc[m] = fmaf(uu.y, vv.y, acc[m]);
          acc[m] = fmaf(uu.z, vv.z, acc[m]);
          acc[m] = fmaf(uu.w, vv.w, acc[m]);
        }
      }
    }
    __syncthreads();
  }
  if (tq < 60) {
#pragma unroll
    for (int m = 0; m < 5; m++) vu_s[tq][sg * 5 + m] = acc[m];
  }
  __syncthreads();
  if (tid < 20) {
    int s = sc * 20 + tid;
    float dec = (s < 50) ? 1.f - (float)(s + 1) / 50.f : 0.f;
    float a = dec, beta = dec;
    float vns = vns_s[tid], bnv = bn[0];
    for (int t = 0; t < T; t++) {
      float g = ap_s[t] * sigmoidf_(vns + cx_s[t] + bnv);
      float wv = (1.f - a) * g;
      a += wv;
      gm_s[t][tid] = aw_s[t][tid] * beta;          // gamma uses PRE-update beta
      beta = beta * (1.f - ra_s[t][tid] * sigmoidf_(beta * vu_s[t][tid])) + wv;
    }
  }
  __syncthreads();
  for (int i = tid; i < T * 20; i += 256) {
    int sl = i / 60, t = i % 60;
    gammaT[((size_t)b * S + sc * 20 + sl) * TP + t] = gm_s[t][sl];
  }
}

// ---------- role scores -> softmax(mean over heads) * p_gen -> out[:, V:] ----------
__global__ void k_role(const float* __restrict__ khf, const float* __restrict__ qh,
                       const float* __restrict__ pgen, float* __restrict__ out) {
  int row = blockIdx.x, tid = threadIdx.x;         // 192 threads
  int b = row / T;
  __shared__ float sc[H * R];
  __shared__ float pr[H * R];
  if (tid < H * R) {
    int h = tid / R, r = tid % R;
    const float* qp = qh + (size_t)row * D + h * DK;
    const float* kp = khf + (size_t)(b * R + r) * D + h * DK;
    float acc = 0.f;
#pragma unroll
    for (int i = 0; i < DK; i++) acc = fmaf(qp[i], kp[i], acc);
    sc[tid] = acc * 0.125f;                        // 1/sqrt(64)
  }
  __syncthreads();
  if (tid < H) {
    float m = -INFINITY;
    for (int r = 0; r < R; r++) m = fmaxf(m, sc[tid * R + r]);
    float ssum = 0.f;
    for (int r = 0; r < R; r++) { float e = expf(sc[tid * R + r] - m); pr[tid * R + r] = e; ssum += e; }
    float inv = 1.f / ssum;
    for (int r = 0; r < R; r++) pr[tid * R + r] *= inv;
  }
  __syncthreads();
  if (tid < R) {
    float acc = 0.f;
#pragma unroll
    for (int h = 0; h < H; h++) acc += pr[h * R + tid];
    out[(size_t)row * VR + V + tid] = acc * (1.f / H) * pgen[row];
  }
}

extern "C" void kernel_launch(void* const* d_in, const int* in_sizes, int n_in,
                              void* d_out, int out_size, void* d_ws, size_t ws_size,
                              hipStream_t stream) {
  const float* v_out  = (const float*)d_in[0];
  const float* f_out  = (const float*)d_in[1];
  const float* q_seq  = (const float*)d_in[2];
  const float* logits = (const float*)d_in[3];
  const float* Wr     = (const float*)d_in[4];
  const float* br     = (const float*)d_in[5];
  const float* Wa     = (const float*)d_in[6];
  const float* ba     = (const float*)d_in[7];
  const float* Wq_lin = (const float*)d_in[8];
  const float* Wn     = (const float*)d_in[9];
  const float* bn     = (const float*)d_in[10];
  const float* Wlogit = (const float*)d_in[11];
  const float* blogit = (const float*)d_in[12];
  const float* Wptr   = (const float*)d_in[13];
  const float* bptr   = (const float*)d_in[14];
  const float* Wqr    = (const float*)d_in[15];
  const float* bqr    = (const float*)d_in[16];
  const float* Wkr    = (const float*)d_in[17];
  const float* bkr    = (const float*)d_in[18];
  float* out = (float*)d_out;
  float* ws  = (float*)d_ws;

  float* attn   = ws;                                  // BT*S
  float* ra     = attn   + (size_t)BT * S;             // BT*S
  float* u      = ra     + (size_t)BT * S;             // BT*D
  float* pgen   = u      + (size_t)BT * D;             // BT
  float* remv   = pgen   + BT;                         // BT
  float* addp   = remv   + BT;                         // BT
  float* ctxn   = addp   + BT;                         // BT
  float* vn     = ctxn   + BT;                         // B*S
  float* vn2    = vn     + B * S;                      // B*S
  float* khf    = vn2    + B * S;                      // B*R*D
  float* qh     = khf    + (size_t)B * R * D;          // BT*D
  float* gammaT = qh     + (size_t)BT * D;             // B*S*TP
  u16*   qwb    = (u16*)(gammaT + (size_t)B * S * TP); // MP*D
  u16*   selb   = qwb  + (size_t)MP * D;               // MP*D
  u16*   fb     = selb + (size_t)MP * D;               // FP*D
  u16*   Wqlb   = fb   + (size_t)FP * D;               // D*D
  u16*   WqrT   = Wqlb + (size_t)D * D;                // D*D
  u16*   WkrT   = WqrT + (size_t)D * D;                // D*D
  u16*   qbf    = WkrT + (size_t)D * D;                // MP*D
  u16*   Wlbf   = qbf  + (size_t)MP * D;               // V*D

  // L1: all input-only work (prep incl Wlogit cvt, vn, attnscal)
  k_combo1<<<NB_PREP + 400 + 240, 256, 0, stream>>>(
      Wlogit, q_seq, Wq_lin, f_out, Wqr, Wkr, logits, v_out,
      Wn, Wr, br, Wa, ba, Wptr, bptr,
      Wlbf, qbf, Wqlb, fb, qwb, selb, WqrT, WkrT,
      vn, vn2, attn, remv, addp, pgen);

  // L2: vocab 1/3 + u-GEMM + kh-GEMM + attnw
  k_combo2<<<667 + 44 + 960, 256, 0, stream>>>(
      qbf, Wlbf, blogit, out, qwb, Wqlb, u, fb, WkrT, bkr, khf,
      attn, vn2, remv, ra, ctxn);

  // L3: rank-1 recurrence (VU + fused add_state/beta chains)
  k_vubeta<<<B * 5, 256, 0, stream>>>(u, v_out, attn, ra, addp, ctxn, vn, bn, gammaT);

  // L4: vocab 1/3 + selgemm
  k_combo3<<<667 + B * 4, 256, 0, stream>>>(qbf, Wlbf, blogit, out, v_out, gammaT, selb);

  // L5: vocab 1/3 + qh-GEMM
  k_combo4<<<666 + 32, 256, 0, stream>>>(qbf, Wlbf, blogit, out, selb, WqrT, bqr, qh);

  // L6: role epilogue
  k_role<<<BT, 192, 0, stream>>>(khf, qh, pgen, out);
}

// Round 13
// 181.715 us; speedup vs baseline: 1.2219x; 1.1785x over previous
//
#include <hip/hip_runtime.h>
#include <math.h>

// Problem constants
constexpr int B = 16, S = 100, T = 60, D = 512, H = 8, V = 32000, R = 20;
constexpr int DK = 64, WIN = 20;
constexpr int VR = V + R;        // 32020
constexpr int BT = B * T;        // 960
constexpr int MP = 1024;         // padded GEMM M
constexpr int TP = 64;           // padded T for gammaT rows
constexpr int FP = 384;          // padded B*R rows for kh GEMM

typedef unsigned short u16;
typedef __attribute__((ext_vector_type(8))) short bf16x8;
typedef __attribute__((ext_vector_type(4))) float f32x4;

__device__ __forceinline__ float wred_sum(float v) {
#pragma unroll
  for (int st = 32; st > 0; st >>= 1) v += __shfl_xor(v, st, 64);
  return v;
}
__device__ __forceinline__ float wred_max(float v) {
#pragma unroll
  for (int st = 32; st > 0; st >>= 1) v = fmaxf(v, __shfl_xor(v, st, 64));
  return v;
}
__device__ __forceinline__ float sigmoidf_(float x) { return 1.f / (1.f + expf(-x)); }
__device__ __forceinline__ u16 f2bf(float x) {
  unsigned u = __float_as_uint(x);
  return (u16)((u + 0x7fffu + ((u >> 16) & 1u)) >> 16);
}
__device__ __forceinline__ void gload_lds16(const u16* g, u16* l) {
  __builtin_amdgcn_global_load_lds((const __attribute__((address_space(1))) void*)g,
                                   (__attribute__((address_space(3))) void*)l, 16, 0, 0);
}

// ================= bodies =================

__device__ __forceinline__ void vn_body(int row, int l, const float* __restrict__ v,
                                        const float* __restrict__ Wn,
                                        float* __restrict__ vn, float* __restrict__ vn2) {
  const float* vr = v + (size_t)row * D + l * 8;
  float p0 = 0.f, p1 = 0.f;
#pragma unroll
  for (int i = 0; i < 8; i++) {
    float x = vr[i];
    p0 = fmaf(x, Wn[l * 8 + i], p0);
    p1 = fmaf(x, Wn[D + l * 8 + i], p1);
  }
  p0 = wred_sum(p0); p1 = wred_sum(p1);
  if (l == 0) { vn[row] = p0; vn2[row] = p1; }
}

__device__ __forceinline__ void attnscal_body(int row, int l,
    const float* __restrict__ logits, const float* __restrict__ q,
    const float* __restrict__ Wr, const float* __restrict__ br,
    const float* __restrict__ Wa, const float* __restrict__ ba,
    const float* __restrict__ Wptr, const float* __restrict__ bptr,
    float* __restrict__ attn_g, float* __restrict__ remv,
    float* __restrict__ addp, float* __restrict__ pgen) {
  const float* src = logits + (size_t)row * S;
  float a = src[l];
  float b2 = (l + 64 < S) ? src[l + 64] : -INFINITY;
  float m = wred_max(fmaxf(a, b2));
  float ea = expf(a - m), eb = (l + 64 < S) ? expf(b2 - m) : 0.f;
  float inv = 1.f / wred_sum(ea + eb);
  attn_g[(size_t)row * S + l] = ea * inv;
  if (l + 64 < S) attn_g[(size_t)row * S + l + 64] = eb * inv;

  const float* qr = q + (size_t)row * D + l * 8;
  float pr = 0.f, pa = 0.f, pp = 0.f;
#pragma unroll
  for (int i = 0; i < 8; i++) {
    float x = qr[i];
    pr = fmaf(x, Wr[l * 8 + i], pr);
    pa = fmaf(x, Wa[l * 8 + i], pa);
    pp = fmaf(x, Wptr[l * 8 + i], pp);
  }
#pragma unroll
  for (int st = 32; st > 0; st >>= 1) {
    pr += __shfl_xor(pr, st, 64);
    pa += __shfl_xor(pa, st, 64);
    pp += __shfl_xor(pp, st, 64);
  }
  if (l == 0) {
    remv[row] = sigmoidf_(pr + br[0]);
    addp[row] = sigmoidf_(pa + ba[0]);
    pgen[row] = sigmoidf_(pp + bptr[0]);
  }
}

__device__ __forceinline__ void attnw_body(int row, int tid, float* red,
    const float* __restrict__ attn, const float* __restrict__ vn2,
    const float* __restrict__ remv, float* __restrict__ ra, float* __restrict__ ctxn) {
  int b = row / T, t = row % T;
  int L = min(t + 1, WIN);
  if (tid < 128) {
    float dnm = 0.f;
    for (int j = 0; j < L; j++) dnm += expf((float)(WIN - j) / 20.f);
    float p = 0.f;
    if (tid < S) {
      float aw = 0.f;
      for (int j = 0; j < L; j++)
        aw = fmaf(expf((float)(WIN - j) / 20.f) / dnm, attn[(size_t)(row - j) * S + tid], aw);
      ra[(size_t)row * S + tid] = remv[row] * aw;
      p = aw * vn2[b * S + tid];
    }
    red[tid] = p;
  }
  __syncthreads();
  if (tid < 64) {
    float v2 = red[tid] + red[tid + 64];
    v2 = wred_sum(v2);
    if (tid == 0) ctxn[row] = v2;
  }
}

constexpr int NB_CVT = 16960;
constexpr int NB_QWB = MP + 64;
constexpr int NB_PREP = NB_CVT + NB_QWB + 128;     // 18176
__device__ __forceinline__ void prep_body(int blk, int tid, float (*tile)[65],
    const float* __restrict__ Wlogit, const float* __restrict__ q,
    const float* __restrict__ Wq, const float* __restrict__ f,
    const float* __restrict__ Wqr, const float* __restrict__ Wkr,
    u16* __restrict__ Wlbf, u16* __restrict__ qbf,
    u16* __restrict__ Wqlb, u16* __restrict__ fb,
    u16* __restrict__ qwb, u16* __restrict__ selb,
    u16* __restrict__ WqrT, u16* __restrict__ WkrT) {
  if (blk < NB_CVT) {
    int idx = blk * 256 + tid;
    constexpr int NW = V * D / 4;
    constexpr int NQ = MP * D / 4;
    constexpr int NWQ = D * D / 4;
    if (idx < NW) {
      float4 x = reinterpret_cast<const float4*>(Wlogit)[idx];
      ushort4 o = {f2bf(x.x), f2bf(x.y), f2bf(x.z), f2bf(x.w)};
      reinterpret_cast<ushort4*>(Wlbf)[idx] = o;
    } else if (idx < NW + NQ) {
      int j = idx - NW;
      int row = (j * 4) / D;
      ushort4 o = {0, 0, 0, 0};
      if (row < BT) {
        float4 x = reinterpret_cast<const float4*>(q)[j];
        o = {f2bf(x.x), f2bf(x.y), f2bf(x.z), f2bf(x.w)};
      }
      reinterpret_cast<ushort4*>(qbf)[j] = o;
    } else if (idx < NW + NQ + NWQ) {
      int j = idx - NW - NQ;
      float4 x = reinterpret_cast<const float4*>(Wq)[j];
      ushort4 o = {f2bf(x.x), f2bf(x.y), f2bf(x.z), f2bf(x.w)};
      reinterpret_cast<ushort4*>(Wqlb)[j] = o;
    } else {
      int j = idx - NW - NQ - NWQ;
      int row = (j * 4) / D;
      ushort4 o = {0, 0, 0, 0};
      if (row < B * R) {
        float4 x = reinterpret_cast<const float4*>(f)[j];
        o = {f2bf(x.x), f2bf(x.y), f2bf(x.z), f2bf(x.w)};
      }
      reinterpret_cast<ushort4*>(fb)[j] = o;
    }
  } else if (blk < NB_CVT + NB_QWB) {
    int row = blk - NB_CVT;
    if (row >= MP) {
      size_t base = (size_t)BT * D + (size_t)(row - MP) * D;
      selb[base + tid] = 0; selb[base + tid + 256] = 0;
      return;
    }
    if (row >= BT) {
      qwb[(size_t)row * D + tid] = 0; qwb[(size_t)row * D + tid + 256] = 0;
      return;
    }
    int t = row % T, L = min(t + 1, WIN);
    float dnm = 0.f;
    for (int j = 0; j < L; j++) dnm += expf((float)(WIN - j) / 20.f);
    float a0 = 0.f, a1 = 0.f;
    for (int j = 0; j < L; j++) {
      float wj = expf((float)(WIN - j) / 20.f) / dnm;
      a0 = fmaf(wj, q[(size_t)(row - j) * D + tid], a0);
      a1 = fmaf(wj, q[(size_t)(row - j) * D + tid + 256], a1);
    }
    qwb[(size_t)row * D + tid] = f2bf(a0);
    qwb[(size_t)row * D + tid + 256] = f2bf(a1);
  } else {
    int qt = blk - NB_CVT - NB_QWB;
    const float* src = (qt < 64) ? Wqr : Wkr;
    u16* dst = (qt < 64) ? WqrT : WkrT;
    int q64 = qt & 63;
    int bx = q64 % 8, by = q64 / 8;
#pragma unroll
    for (int i = 0; i < 16; i++) {
      int e = i * 256 + tid, r = e >> 6, c = e & 63;
      tile[r][c] = src[(size_t)(by * 64 + r) * D + bx * 64 + c];
    }
    __syncthreads();
#pragma unroll
    for (int i = 0; i < 16; i++) {
      int e = i * 256 + tid, r = e >> 6, c = e & 63;
      dst[(size_t)(bx * 64 + r) * D + by * 64 + c] = f2bf(tile[c][r]);
    }
  }
}

__device__ __forceinline__ void gemm512_body(const u16* __restrict__ A, const u16* __restrict__ Bw,
                                             const float* __restrict__ bias, float* __restrict__ outp,
                                             int mlimit, int mt, int nt, int tid, u16* ldsbuf) {
  u16* As = ldsbuf;
  u16* Bs = ldsbuf + 128 * 64;
  int m0 = mt * 128, n0 = nt * 128;
  int l = tid & 63;
  int w = tid >> 6, wm = w >> 1, wn = w & 1;
  f32x4 acc[4][4];
#pragma unroll
  for (int mb = 0; mb < 4; mb++)
#pragma unroll
    for (int nb = 0; nb < 4; nb++) acc[mb][nb] = (f32x4){0.f, 0.f, 0.f, 0.f};

  for (int k0 = 0; k0 < D; k0 += 64) {
#pragma unroll
    for (int i = 0; i < 4; i++) {
      int chunk = i * 256 + tid;
      int row = chunk >> 3, kc = chunk & 7;
      int kcs = kc ^ (row & 7);
      gload_lds16(A + (size_t)(m0 + row) * D + k0 + kcs * 8, As + chunk * 8);
      gload_lds16(Bw + (size_t)(n0 + row) * D + k0 + kcs * 8, Bs + chunk * 8);
    }
    __syncthreads();
#pragma unroll
    for (int kk = 0; kk < 2; kk++) {
      bf16x8 af[4], bfr[4];
#pragma unroll
      for (int mb = 0; mb < 4; mb++) {
        int row = wm * 64 + mb * 16 + (l & 15);
        int kc0 = kk * 4 + (l >> 4);
        af[mb] = *(const bf16x8*)(As + row * 64 + ((kc0 ^ (row & 7)) << 3));
      }
#pragma unroll
      for (int nb = 0; nb < 4; nb++) {
        int row = wn * 64 + nb * 16 + (l & 15);
        int kc0 = kk * 4 + (l >> 4);
        bfr[nb] = *(const bf16x8*)(Bs + row * 64 + ((kc0 ^ (row & 7)) << 3));
      }
#pragma unroll
      for (int mb = 0; mb < 4; mb++)
#pragma unroll
        for (int nb = 0; nb < 4; nb++)
          acc[mb][nb] = __builtin_amdgcn_mfma_f32_16x16x32_bf16(af[mb], bfr[nb], acc[mb][nb], 0, 0, 0);
    }
    __syncthreads();
  }

  float* ch = (float*)ldsbuf;
#pragma unroll
  for (int c = 0; c < 4; c++) {
    if (wm == (c >> 1)) {
#pragma unroll
      for (int nb = 0; nb < 4; nb++) {
        int col = wn * 64 + nb * 16 + (l & 15);
        float bl = bias ? bias[n0 + col] : 0.f;
#pragma unroll
        for (int mbi = 0; mbi < 2; mbi++) {
          int mb = (c & 1) * 2 + mbi;
#pragma unroll
          for (int q2 = 0; q2 < 4; q2++) {
            int row_local = mb * 16 + (l >> 4) * 4 + q2 - (c & 1) * 32;
            ch[row_local * 132 + col] = acc[mb][nb][q2] + bl;
          }
        }
      }
    }
    __syncthreads();
#pragma unroll
    for (int p = 0; p < 4; p++) {
      int r = p * 8 + (tid >> 5);
      int m = m0 + c * 32 + r;
      if (m < mlimit) {
        int seg = tid & 31;
        *(float4*)(outp + (size_t)m * D + n0 + seg * 4) =
            *(const float4*)(ch + r * 132 + seg * 4);
      }
    }
    __syncthreads();
  }
}

__device__ __forceinline__ void vocab_body(int bid, int tid, u16* ldsbuf,
    const u16* __restrict__ A, const u16* __restrict__ Bw,
    const float* __restrict__ blog, float* __restrict__ out) {
  u16* As = ldsbuf;
  u16* Bs = ldsbuf + 128 * 64;
  int swz = (bid & 7) * 250 + (bid >> 3);          // bijective on [0,2000)
  int m0 = (swz & 7) * 128, n0 = (swz >> 3) * 128;
  int l = tid & 63;
  int w = tid >> 6, wm = w >> 1, wn = w & 1;

  f32x4 acc[4][4];
#pragma unroll
  for (int mb = 0; mb < 4; mb++)
#pragma unroll
    for (int nb = 0; nb < 4; nb++) acc[mb][nb] = (f32x4){0.f, 0.f, 0.f, 0.f};

  for (int k0 = 0; k0 < D; k0 += 64) {
#pragma unroll
    for (int i = 0; i < 4; i++) {
      int chunk = i * 256 + tid;
      int row = chunk >> 3, kc = chunk & 7;
      int kcs = kc ^ (row & 7);
      gload_lds16(A + (size_t)(m0 + row) * D + k0 + kcs * 8, As + chunk * 8);
      gload_lds16(Bw + (size_t)(n0 + row) * D + k0 + kcs * 8, Bs + chunk * 8);
    }
    __syncthreads();
#pragma unroll
    for (int kk = 0; kk < 2; kk++) {
      bf16x8 af[4], bfr[4];
#pragma unroll
      for (int mb = 0; mb < 4; mb++) {
        int row = wm * 64 + mb * 16 + (l & 15);
        int kc0 = kk * 4 + (l >> 4);
        af[mb] = *(const bf16x8*)(As + row * 64 + ((kc0 ^ (row & 7)) << 3));
      }
#pragma unroll
      for (int nb = 0; nb < 4; nb++) {
        int row = wn * 64 + nb * 16 + (l & 15);
        int kc0 = kk * 4 + (l >> 4);
        bfr[nb] = *(const bf16x8*)(Bs + row * 64 + ((kc0 ^ (row & 7)) << 3));
      }
#pragma unroll
      for (int mb = 0; mb < 4; mb++)
#pragma unroll
        for (int nb = 0; nb < 4; nb++)
          acc[mb][nb] = __builtin_amdgcn_mfma_f32_16x16x32_bf16(af[mb], bfr[nb], acc[mb][nb], 0, 0, 0);
    }
    __syncthreads();
  }

  float* ch = (float*)ldsbuf;
#pragma unroll
  for (int c = 0; c < 4; c++) {
    if (wm == (c >> 1)) {
#pragma unroll
      for (int nb = 0; nb < 4; nb++) {
        int col = wn * 64 + nb * 16 + (l & 15);
        float bl = blog[n0 + col];
#pragma unroll
        for (int mbi = 0; mbi < 2; mbi++) {
          int mb = (c & 1) * 2 + mbi;
#pragma unroll
          for (int q2 = 0; q2 < 4; q2++) {
            int row_local = mb * 16 + (l >> 4) * 4 + q2 - (c & 1) * 32;
            ch[row_local * 132 + col] = acc[mb][nb][q2] + bl;
          }
        }
      }
    }
    __syncthreads();
#pragma unroll
    for (int p = 0; p < 4; p++) {
      int r = p * 8 + (tid >> 5);
      int m = m0 + c * 32 + r;
      if (m < BT) {
        int seg = tid & 31;
        *(float4*)(out + (size_t)m * VR + n0 + seg * 4) =
            *(const float4*)(ch + r * 132 + seg * 4);
      }
    }
    __syncthreads();
  }
}

__device__ __forceinline__ void selgemm_body(int bq, int tid, float* gT /*[S][TP]*/,
    const float* __restrict__ v, const float* __restrict__ gammaT, u16* __restrict__ selb) {
  int b = bq >> 2, dc = bq & 3;
  int dl = tid & 127, th0 = tid >> 7;
  int d = dc * 128 + dl;
  for (int i = tid; i < S * TP; i += 256) {
    int r = i >> 6, c = i & 63;
    gT[r * TP + c] = gammaT[((size_t)b * S + r) * TP + c];
  }
  __syncthreads();
  float acc[2][16];
#pragma unroll
  for (int g = 0; g < 2; g++)
#pragma unroll
    for (int m = 0; m < 16; m++) acc[g][m] = 0.f;
  for (int ss = 0; ss < S; ss++) {
    float vv = v[((size_t)b * S + ss) * D + d];
#pragma unroll
    for (int g = 0; g < 2; g++) {
      int tg = th0 + 2 * g;
      const float* gp = gT + ss * TP + tg * 16;
      float4 g0 = *(const float4*)gp;
      float4 g1 = *(const float4*)(gp + 4);
      float4 g2 = *(const float4*)(gp + 8);
      float4 g3 = *(const float4*)(gp + 12);
      acc[g][0]  = fmaf(g0.x, vv, acc[g][0]);  acc[g][1]  = fmaf(g0.y, vv, acc[g][1]);
      acc[g][2]  = fmaf(g0.z, vv, acc[g][2]);  acc[g][3]  = fmaf(g0.w, vv, acc[g][3]);
      acc[g][4]  = fmaf(g1.x, vv, acc[g][4]);  acc[g][5]  = fmaf(g1.y, vv, acc[g][5]);
      acc[g][6]  = fmaf(g1.z, vv, acc[g][6]);  acc[g][7]  = fmaf(g1.w, vv, acc[g][7]);
      acc[g][8]  = fmaf(g2.x, vv, acc[g][8]);  acc[g][9]  = fmaf(g2.y, vv, acc[g][9]);
      acc[g][10] = fmaf(g2.z, vv, acc[g][10]); acc[g][11] = fmaf(g2.w, vv, acc[g][11]);
      acc[g][12] = fmaf(g3.x, vv, acc[g][12]); acc[g][13] = fmaf(g3.y, vv, acc[g][13]);
      acc[g][14] = fmaf(g3.z, vv, acc[g][14]); acc[g][15] = fmaf(g3.w, vv, acc[g][15]);
    }
  }
#pragma unroll
  for (int g = 0; g < 2; g++) {
    int tg = th0 + 2 * g;
#pragma unroll
    for (int m = 0; m < 16; m++) {
      int t = tg * 16 + m;
      if (t < T) selb[((size_t)b * T + t) * D + d] = f2bf(acc[g][m]);
    }
  }
}

// ---- vubeta: K-chunks of 128, float4 staged, fully-unrolled independent loads ----
// smem layout (floats): u_s[60][132] @0, v_s[20][132] @7920, aw[60][20] @10560,
// ra[60][20] @11760, vu[60][20] @12960, gm[60][20] @14160, ap[60] @15360,
// cx[60] @15420, vns[20] @15480  — total 15500 floats = 62 KB
__device__ __forceinline__ void vubeta_body(int bq, int tid, float* sm,
    const float* __restrict__ u, const float* __restrict__ v,
    const float* __restrict__ attn, const float* __restrict__ ra,
    const float* __restrict__ addp, const float* __restrict__ ctxn,
    const float* __restrict__ vn, const float* __restrict__ bn,
    float* __restrict__ gammaT) {
  int b = bq / 5, sc = bq % 5;
  int tq = tid >> 2, sg = tid & 3;
  float* u_s = sm;               // [60][132]
  float* v_s = sm + 7920;        // [20][132]
  float* aw_s = sm + 10560;      // [60][20]
  float* ra_s = sm + 11760;
  float* vu_s = sm + 12960;
  float* gm_s = sm + 14160;
  float* ap_s = sm + 15360;
  float* cx_s = sm + 15420;
  float* vns_s = sm + 15480;
  // per-(t,s) scalars: 1200 elems, 5 unrolled independent iterations
#pragma unroll
  for (int ii = 0; ii < 5; ii++) {
    int i = ii * 256 + tid;
    if (i < T * 20) {
      int t = i / 20, sl = i % 20;
      size_t base = ((size_t)b * T + t) * S + sc * 20 + sl;
      aw_s[t * 20 + sl] = attn[base];
      ra_s[t * 20 + sl] = ra[base];
    }
  }
  if (tid < T) { ap_s[tid] = addp[b * T + tid]; cx_s[tid] = ctxn[b * T + tid]; }
  if (tid >= 64 && tid < 84) vns_s[tid - 64] = vn[b * S + sc * 20 + tid - 64];

  float acc[5] = {0, 0, 0, 0, 0};
  for (int kc = 0; kc < 4; kc++) {                 // 128-wide K chunks
    // u: 60 rows x 32 float4 = 1920 float4s, 8 independent unrolled loads/thread
#pragma unroll
    for (int ii = 0; ii < 8; ii++) {
      int i = ii * 256 + tid;
      if (i < 60 * 32) {
        int r = i >> 5, c = (i & 31) * 4;
        *(float4*)&u_s[r * 132 + c] =
            *(const float4*)&u[((size_t)b * T + r) * D + kc * 128 + c];
      }
    }
    // v: 20 rows x 32 float4 = 640 float4s, 3 unrolled loads/thread
#pragma unroll
    for (int ii = 0; ii < 3; ii++) {
      int i = ii * 256 + tid;
      if (i < 20 * 32) {
        int r = i >> 5, c = (i & 31) * 4;
        *(float4*)&v_s[r * 132 + c] =
            *(const float4*)&v[((size_t)b * S + sc * 20 + r) * D + kc * 128 + c];
      }
    }
    __syncthreads();
    if (tq < 60) {
#pragma unroll
      for (int e0 = 0; e0 < 128; e0 += 4) {
        float4 uu = *(const float4*)&u_s[tq * 132 + e0];
#pragma unroll
        for (int m = 0; m < 5; m++) {
          float4 vv = *(const float4*)&v_s[(sg * 5 + m) * 132 + e0];
          acc[m] = fmaf(uu.x, vv.x, acc[m]);
          acc[m] = fmaf(uu.y, vv.y, acc[m]);
          acc[m] = fmaf(uu.z, vv.z, acc[m]);
          acc[m] = fmaf(uu.w, vv.w, acc[m]);
        }
      }
    }
    __syncthreads();
  }
  if (tq < 60) {
#pragma unroll
    for (int m = 0; m < 5; m++) vu_s[tq * 20 + sg * 5 + m] = acc[m];
  }
  __syncthreads();
  // fused add_state + beta chains (20 lanes, all data in LDS)
  if (tid < 20) {
    int s = sc * 20 + tid;
    float dec = (s < 50) ? 1.f - (float)(s + 1) / 50.f : 0.f;
    float a = dec, beta = dec;
    float vns = vns_s[tid], bnv = bn[0];
    for (int t = 0; t < T; t++) {
      float g = ap_s[t] * sigmoidf_(vns + cx_s[t] + bnv);
      float wv = (1.f - a) * g;
      a += wv;
      gm_s[t * 20 + tid] = aw_s[t * 20 + tid] * beta;   // gamma uses PRE-update beta
      beta = beta * (1.f - ra_s[t * 20 + tid] * sigmoidf_(beta * vu_s[t * 20 + tid])) + wv;
    }
  }
  __syncthreads();
#pragma unroll
  for (int ii = 0; ii < 5; ii++) {
    int i = ii * 256 + tid;
    if (i < T * 20) {
      int sl = i / 60, t = i % 60;
      gammaT[((size_t)b * S + sc * 20 + sl) * TP + t] = gm_s[t * 20 + sl];
    }
  }
}

// ================= dispatch kernels =================

// combo1: prep (incl Wlogit cvt) + vn + attnscal — all input-only
__global__ __launch_bounds__(256) void k_combo1(
    const float* Wlogit, const float* q, const float* Wq, const float* f,
    const float* Wqr, const float* Wkr, const float* logits, const float* v,
    const float* Wn, const float* Wr, const float* br, const float* Wa, const float* ba,
    const float* Wptr, const float* bptr,
    u16* Wlbf, u16* qbf, u16* Wqlb, u16* fb, u16* qwb, u16* selb, u16* WqrT, u16* WkrT,
    float* vn, float* vn2, float* attn_g, float* remv, float* addp, float* pgen) {
  __shared__ float tile[64][65];
  int blk = blockIdx.x, tid = threadIdx.x;
  if (blk < NB_PREP) {
    prep_body(blk, tid, tile, Wlogit, q, Wq, f, Wqr, Wkr,
              Wlbf, qbf, Wqlb, fb, qwb, selb, WqrT, WkrT);
  } else if (blk < NB_PREP + 400) {
    int row = (blk - NB_PREP) * 4 + (tid >> 6);    // 1600 rows
    vn_body(row, tid & 63, v, Wn, vn, vn2);
  } else {
    int row = (blk - NB_PREP - 400) * 4 + (tid >> 6);  // 960 rows
    attnscal_body(row, tid & 63, logits, q, Wr, br, Wa, ba, Wptr, bptr,
                  attn_g, remv, addp, pgen);
  }
}

// combo2: vocab [0,600) + gemm512 dual (44) + attnw (960)
__global__ __launch_bounds__(256) void k_combo2(
    const u16* qbf, const u16* Wlbf, const float* blog, float* out,
    const u16* qwb, const u16* Wqlb, float* u,
    const u16* fb, const u16* WkrT, const float* bkr, float* khf,
    const float* attn, const float* vn2, const float* remv, float* ra, float* ctxn) {
  __shared__ u16 lds[2 * 128 * 64];
  int blk = blockIdx.x, tid = threadIdx.x;
  if (blk < 600) {
    vocab_body(blk, tid, lds, qbf, Wlbf, blog, out);
  } else if (blk < 644) {
    int z = blk - 600, xx = z % 11, yy = z / 11;
    if (xx < 8) gemm512_body(qwb, Wqlb, nullptr, u, BT, xx, yy, tid, lds);
    else        gemm512_body(fb, WkrT, bkr, khf, B * R, xx - 8, yy, tid, lds);
  } else {
    attnw_body(blk - 644, tid, (float*)lds, attn, vn2, remv, ra, ctxn);
  }
}

// vubetap: vubeta (80) + vocab [600,800)
__global__ __launch_bounds__(256) void k_vubetap(
    const float* u, const float* v, const float* attn, const float* ra,
    const float* addp, const float* ctxn, const float* vn, const float* bn,
    float* gammaT,
    const u16* qbf, const u16* Wlbf, const float* blog, float* out) {
  __shared__ float smem[15500];                    // 62 KB (vubeta) / vocab uses 32 KB
  int blk = blockIdx.x, tid = threadIdx.x;
  if (blk < 80) vubeta_body(blk, tid, smem, u, v, attn, ra, addp, ctxn, vn, bn, gammaT);
  else          vocab_body(600 + blk - 80, tid, (u16*)smem, qbf, Wlbf, blog, out);
}

// combo3: vocab [800,1400) + selgemm (64)
__global__ __launch_bounds__(256) void k_combo3(
    const u16* qbf, const u16* Wlbf, const float* blog, float* out,
    const float* v, const float* gammaT, u16* selb) {
  __shared__ u16 lds[2 * 128 * 64];
  int blk = blockIdx.x, tid = threadIdx.x;
  if (blk < 600) vocab_body(800 + blk, tid, lds, qbf, Wlbf, blog, out);
  else           selgemm_body(blk - 600, tid, (float*)lds, v, gammaT, selb);
}

// combo4: vocab [1400,2000) + qh gemm512 (32)
__global__ __launch_bounds__(256) void k_combo4(
    const u16* qbf, const u16* Wlbf, const float* blog, float* out,
    const u16* selb, const u16* WqrT, const float* bqr, float* qh) {
  __shared__ u16 lds[2 * 128 * 64];
  int blk = blockIdx.x, tid = threadIdx.x;
  if (blk < 600) vocab_body(1400 + blk, tid, lds, qbf, Wlbf, blog, out);
  else {
    int z = blk - 600;
    gemm512_body(selb, WqrT, bqr, qh, BT, z % 8, z / 8, tid, lds);
  }
}

// ---------- role epilogue ----------
__global__ void k_role(const float* __restrict__ khf, const float* __restrict__ qh,
                       const float* __restrict__ pgen, float* __restrict__ out) {
  int row = blockIdx.x, tid = threadIdx.x;         // 192 threads
  int b = row / T;
  __shared__ float sc[H * R];
  __shared__ float pr[H * R];
  if (tid < H * R) {
    int h = tid / R, r = tid % R;
    const float* qp = qh + (size_t)row * D + h * DK;
    const float* kp = khf + (size_t)(b * R + r) * D + h * DK;
    float acc = 0.f;
#pragma unroll
    for (int i = 0; i < DK; i++) acc = fmaf(qp[i], kp[i], acc);
    sc[tid] = acc * 0.125f;                        // 1/sqrt(64)
  }
  __syncthreads();
  if (tid < H) {
    float m = -INFINITY;
    for (int r = 0; r < R; r++) m = fmaxf(m, sc[tid * R + r]);
    float ssum = 0.f;
    for (int r = 0; r < R; r++) { float e = expf(sc[tid * R + r] - m); pr[tid * R + r] = e; ssum += e; }
    float inv = 1.f / ssum;
    for (int r = 0; r < R; r++) pr[tid * R + r] *= inv;
  }
  __syncthreads();
  if (tid < R) {
    float acc = 0.f;
#pragma unroll
    for (int h = 0; h < H; h++) acc += pr[h * R + tid];
    out[(size_t)row * VR + V + tid] = acc * (1.f / H) * pgen[row];
  }
}

extern "C" void kernel_launch(void* const* d_in, const int* in_sizes, int n_in,
                              void* d_out, int out_size, void* d_ws, size_t ws_size,
                              hipStream_t stream) {
  const float* v_out  = (const float*)d_in[0];
  const float* f_out  = (const float*)d_in[1];
  const float* q_seq  = (const float*)d_in[2];
  const float* logits = (const float*)d_in[3];
  const float* Wr     = (const float*)d_in[4];
  const float* br     = (const float*)d_in[5];
  const float* Wa     = (const float*)d_in[6];
  const float* ba     = (const float*)d_in[7];
  const float* Wq_lin = (const float*)d_in[8];
  const float* Wn     = (const float*)d_in[9];
  const float* bn     = (const float*)d_in[10];
  const float* Wlogit = (const float*)d_in[11];
  const float* blogit = (const float*)d_in[12];
  const float* Wptr   = (const float*)d_in[13];
  const float* bptr   = (const float*)d_in[14];
  const float* Wqr    = (const float*)d_in[15];
  const float* bqr    = (const float*)d_in[16];
  const float* Wkr    = (const float*)d_in[17];
  const float* bkr    = (const float*)d_in[18];
  float* out = (float*)d_out;
  float* ws  = (float*)d_ws;

  float* attn   = ws;                                  // BT*S
  float* ra     = attn   + (size_t)BT * S;             // BT*S
  float* u      = ra     + (size_t)BT * S;             // BT*D
  float* pgen   = u      + (size_t)BT * D;             // BT
  float* remv   = pgen   + BT;                         // BT
  float* addp   = remv   + BT;                         // BT
  float* ctxn   = addp   + BT;                         // BT
  float* vn     = ctxn   + BT;                         // B*S
  float* vn2    = vn     + B * S;                      // B*S
  float* khf    = vn2    + B * S;                      // B*R*D
  float* qh     = khf    + (size_t)B * R * D;          // BT*D
  float* gammaT = qh     + (size_t)BT * D;             // B*S*TP
  u16*   qwb    = (u16*)(gammaT + (size_t)B * S * TP); // MP*D
  u16*   selb   = qwb  + (size_t)MP * D;               // MP*D
  u16*   fb     = selb + (size_t)MP * D;               // FP*D
  u16*   Wqlb   = fb   + (size_t)FP * D;               // D*D
  u16*   WqrT   = Wqlb + (size_t)D * D;                // D*D
  u16*   WkrT   = WqrT + (size_t)D * D;                // D*D
  u16*   qbf    = WkrT + (size_t)D * D;                // MP*D
  u16*   Wlbf   = qbf  + (size_t)MP * D;               // V*D

  // L1: all input-only work (prep incl Wlogit cvt, vn, attnscal)
  k_combo1<<<NB_PREP + 400 + 240, 256, 0, stream>>>(
      Wlogit, q_seq, Wq_lin, f_out, Wqr, Wkr, logits, v_out,
      Wn, Wr, br, Wa, ba, Wptr, bptr,
      Wlbf, qbf, Wqlb, fb, qwb, selb, WqrT, WkrT,
      vn, vn2, attn, remv, addp, pgen);

  // L2: vocab 600 + u-GEMM + kh-GEMM + attnw
  k_combo2<<<600 + 44 + 960, 256, 0, stream>>>(
      qbf, Wlbf, blogit, out, qwb, Wqlb, u, fb, WkrT, bkr, khf,
      attn, vn2, remv, ra, ctxn);

  // L3: vubeta (vectorized staging) + vocab 200
  k_vubetap<<<80 + 200, 256, 0, stream>>>(
      u, v_out, attn, ra, addp, ctxn, vn, bn, gammaT, qbf, Wlbf, blogit, out);

  // L4: vocab 600 + selgemm
  k_combo3<<<600 + B * 4, 256, 0, stream>>>(qbf, Wlbf, blogit, out, v_out, gammaT, selb);

  // L5: vocab 600 + qh-GEMM
  k_combo4<<<600 + 32, 256, 0, stream>>>(qbf, Wlbf, blogit, out, selb, WqrT, bqr, qh);

  // L6: role epilogue
  k_role<<<BT, 192, 0, stream>>>(khf, qh, pgen, out);
}

// Round 14
// 172.242 us; speedup vs baseline: 1.2891x; 1.0550x over previous
//
#include <hip/hip_runtime.h>
#include <math.h>

// Problem constants
constexpr int B = 16, S = 100, T = 60, D = 512, H = 8, V = 32000, R = 20;
constexpr int DK = 64, WIN = 20;
constexpr int VR = V + R;        // 32020
constexpr int BT = B * T;        // 960
constexpr int MP = 1024;         // padded GEMM M
constexpr int TP = 64;           // padded T for gammaT rows
constexpr int FP = 384;          // padded B*R rows for kh GEMM
constexpr int VBP = 1664;        // padded B*S rows for vWqr GEMM (13*128)

typedef unsigned short u16;
typedef __attribute__((ext_vector_type(8))) short bf16x8;
typedef __attribute__((ext_vector_type(4))) float f32x4;

__device__ __forceinline__ float wred_sum(float v) {
#pragma unroll
  for (int st = 32; st > 0; st >>= 1) v += __shfl_xor(v, st, 64);
  return v;
}
__device__ __forceinline__ float wred_max(float v) {
#pragma unroll
  for (int st = 32; st > 0; st >>= 1) v = fmaxf(v, __shfl_xor(v, st, 64));
  return v;
}
__device__ __forceinline__ float sigmoidf_(float x) { return 1.f / (1.f + expf(-x)); }
__device__ __forceinline__ u16 f2bf(float x) {
  unsigned u = __float_as_uint(x);
  return (u16)((u + 0x7fffu + ((u >> 16) & 1u)) >> 16);
}
__device__ __forceinline__ void gload_lds16(const u16* g, u16* l) {
  __builtin_amdgcn_global_load_lds((const __attribute__((address_space(1))) void*)g,
                                   (__attribute__((address_space(3))) void*)l, 16, 0, 0);
}

// ================= bodies =================

__device__ __forceinline__ void vn_body(int row, int l, const float* __restrict__ v,
                                        const float* __restrict__ Wn,
                                        float* __restrict__ vn, float* __restrict__ vn2) {
  const float* vr = v + (size_t)row * D + l * 8;
  float p0 = 0.f, p1 = 0.f;
#pragma unroll
  for (int i = 0; i < 8; i++) {
    float x = vr[i];
    p0 = fmaf(x, Wn[l * 8 + i], p0);
    p1 = fmaf(x, Wn[D + l * 8 + i], p1);
  }
  p0 = wred_sum(p0); p1 = wred_sum(p1);
  if (l == 0) { vn[row] = p0; vn2[row] = p1; }
}

__device__ __forceinline__ void attnscal_body(int row, int l,
    const float* __restrict__ logits, const float* __restrict__ q,
    const float* __restrict__ Wr, const float* __restrict__ br,
    const float* __restrict__ Wa, const float* __restrict__ ba,
    const float* __restrict__ Wptr, const float* __restrict__ bptr,
    float* __restrict__ attn_g, float* __restrict__ remv,
    float* __restrict__ addp, float* __restrict__ pgen) {
  const float* src = logits + (size_t)row * S;
  float a = src[l];
  float b2 = (l + 64 < S) ? src[l + 64] : -INFINITY;
  float m = wred_max(fmaxf(a, b2));
  float ea = expf(a - m), eb = (l + 64 < S) ? expf(b2 - m) : 0.f;
  float inv = 1.f / wred_sum(ea + eb);
  attn_g[(size_t)row * S + l] = ea * inv;
  if (l + 64 < S) attn_g[(size_t)row * S + l + 64] = eb * inv;

  const float* qr = q + (size_t)row * D + l * 8;
  float pr = 0.f, pa = 0.f, pp = 0.f;
#pragma unroll
  for (int i = 0; i < 8; i++) {
    float x = qr[i];
    pr = fmaf(x, Wr[l * 8 + i], pr);
    pa = fmaf(x, Wa[l * 8 + i], pa);
    pp = fmaf(x, Wptr[l * 8 + i], pp);
  }
#pragma unroll
  for (int st = 32; st > 0; st >>= 1) {
    pr += __shfl_xor(pr, st, 64);
    pa += __shfl_xor(pa, st, 64);
    pp += __shfl_xor(pp, st, 64);
  }
  if (l == 0) {
    remv[row] = sigmoidf_(pr + br[0]);
    addp[row] = sigmoidf_(pa + ba[0]);
    pgen[row] = sigmoidf_(pp + bptr[0]);
  }
}

__device__ __forceinline__ void attnw_body(int row, int tid, float* red,
    const float* __restrict__ attn, const float* __restrict__ vn2,
    const float* __restrict__ remv, float* __restrict__ ra, float* __restrict__ ctxn) {
  int b = row / T, t = row % T;
  int L = min(t + 1, WIN);
  if (tid < 128) {
    float dnm = 0.f;
    for (int j = 0; j < L; j++) dnm += expf((float)(WIN - j) / 20.f);
    float p = 0.f;
    if (tid < S) {
      float aw = 0.f;
      for (int j = 0; j < L; j++)
        aw = fmaf(expf((float)(WIN - j) / 20.f) / dnm, attn[(size_t)(row - j) * S + tid], aw);
      ra[(size_t)row * S + tid] = remv[row] * aw;
      p = aw * vn2[b * S + tid];
    }
    red[tid] = p;
  }
  __syncthreads();
  if (tid < 64) {
    float v2 = red[tid] + red[tid + 64];
    v2 = wred_sum(v2);
    if (tid == 0) ctxn[row] = v2;
  }
}

// ---- prep (conversions incl Wlogit & v->bf16, qw window, weight transposes) ----
constexpr int NW = V * D / 4;                      // 4,096,000
constexpr int NQ = MP * D / 4;                     // 131,072
constexpr int NWQ = D * D / 4;                     // 65,536
constexpr int NF = FP * D / 4;                     // 49,152
constexpr int NVB = VBP * D / 4;                   // 212,992
constexpr int NB_CVT = (NW + NQ + NWQ + NF + NVB) / 256;  // 17792 exact
constexpr int NB_QWB = MP;
constexpr int NB_PREP = NB_CVT + NB_QWB + 128;     // 18944
__device__ __forceinline__ void prep_body(int blk, int tid, float (*tile)[65],
    const float* __restrict__ Wlogit, const float* __restrict__ q,
    const float* __restrict__ Wq, const float* __restrict__ f, const float* __restrict__ v,
    const float* __restrict__ Wqr, const float* __restrict__ Wkr,
    u16* __restrict__ Wlbf, u16* __restrict__ qbf,
    u16* __restrict__ Wqlb, u16* __restrict__ fb, u16* __restrict__ vb,
    u16* __restrict__ qwb, u16* __restrict__ WqrT, u16* __restrict__ WkrT) {
  if (blk < NB_CVT) {
    int idx = blk * 256 + tid;
    if (idx < NW) {
      float4 x = reinterpret_cast<const float4*>(Wlogit)[idx];
      ushort4 o = {f2bf(x.x), f2bf(x.y), f2bf(x.z), f2bf(x.w)};
      reinterpret_cast<ushort4*>(Wlbf)[idx] = o;
    } else if (idx < NW + NQ) {
      int j = idx - NW;
      int row = (j * 4) / D;
      ushort4 o = {0, 0, 0, 0};
      if (row < BT) {
        float4 x = reinterpret_cast<const float4*>(q)[j];
        o = {f2bf(x.x), f2bf(x.y), f2bf(x.z), f2bf(x.w)};
      }
      reinterpret_cast<ushort4*>(qbf)[j] = o;
    } else if (idx < NW + NQ + NWQ) {
      int j = idx - NW - NQ;
      float4 x = reinterpret_cast<const float4*>(Wq)[j];
      ushort4 o = {f2bf(x.x), f2bf(x.y), f2bf(x.z), f2bf(x.w)};
      reinterpret_cast<ushort4*>(Wqlb)[j] = o;
    } else if (idx < NW + NQ + NWQ + NF) {
      int j = idx - NW - NQ - NWQ;
      int row = (j * 4) / D;
      ushort4 o = {0, 0, 0, 0};
      if (row < B * R) {
        float4 x = reinterpret_cast<const float4*>(f)[j];
        o = {f2bf(x.x), f2bf(x.y), f2bf(x.z), f2bf(x.w)};
      }
      reinterpret_cast<ushort4*>(fb)[j] = o;
    } else {
      int j = idx - NW - NQ - NWQ - NF;            // 0 .. NVB-1
      int row = (j * 4) / D;
      ushort4 o = {0, 0, 0, 0};
      if (row < B * S) {
        float4 x = reinterpret_cast<const float4*>(v)[j];
        o = {f2bf(x.x), f2bf(x.y), f2bf(x.z), f2bf(x.w)};
      }
      reinterpret_cast<ushort4*>(vb)[j] = o;
    }
  } else if (blk < NB_CVT + NB_QWB) {
    int row = blk - NB_CVT;
    if (row >= BT) {
      qwb[(size_t)row * D + tid] = 0; qwb[(size_t)row * D + tid + 256] = 0;
      return;
    }
    int t = row % T, L = min(t + 1, WIN);
    float dnm = 0.f;
    for (int j = 0; j < L; j++) dnm += expf((float)(WIN - j) / 20.f);
    float a0 = 0.f, a1 = 0.f;
    for (int j = 0; j < L; j++) {
      float wj = expf((float)(WIN - j) / 20.f) / dnm;
      a0 = fmaf(wj, q[(size_t)(row - j) * D + tid], a0);
      a1 = fmaf(wj, q[(size_t)(row - j) * D + tid + 256], a1);
    }
    qwb[(size_t)row * D + tid] = f2bf(a0);
    qwb[(size_t)row * D + tid + 256] = f2bf(a1);
  } else {
    int qt = blk - NB_CVT - NB_QWB;                // 0..127
    const float* src = (qt < 64) ? Wqr : Wkr;
    u16* dst = (qt < 64) ? WqrT : WkrT;
    int q64 = qt & 63;
    int bx = q64 % 8, by = q64 / 8;
#pragma unroll
    for (int i = 0; i < 16; i++) {
      int e = i * 256 + tid, r = e >> 6, c = e & 63;
      tile[r][c] = src[(size_t)(by * 64 + r) * D + bx * 64 + c];
    }
    __syncthreads();
#pragma unroll
    for (int i = 0; i < 16; i++) {
      int e = i * 256 + tid, r = e >> 6, c = e & 63;
      dst[(size_t)(bx * 64 + r) * D + by * 64 + c] = f2bf(tile[c][r]);
    }
  }
}

__device__ __forceinline__ void gemm512_body(const u16* __restrict__ A, const u16* __restrict__ Bw,
                                             const float* __restrict__ bias, float* __restrict__ outp,
                                             int mlimit, int mt, int nt, int tid, u16* ldsbuf) {
  u16* As = ldsbuf;
  u16* Bs = ldsbuf + 128 * 64;
  int m0 = mt * 128, n0 = nt * 128;
  int l = tid & 63;
  int w = tid >> 6, wm = w >> 1, wn = w & 1;
  f32x4 acc[4][4];
#pragma unroll
  for (int mb = 0; mb < 4; mb++)
#pragma unroll
    for (int nb = 0; nb < 4; nb++) acc[mb][nb] = (f32x4){0.f, 0.f, 0.f, 0.f};

  for (int k0 = 0; k0 < D; k0 += 64) {
#pragma unroll
    for (int i = 0; i < 4; i++) {
      int chunk = i * 256 + tid;
      int row = chunk >> 3, kc = chunk & 7;
      int kcs = kc ^ (row & 7);
      gload_lds16(A + (size_t)(m0 + row) * D + k0 + kcs * 8, As + chunk * 8);
      gload_lds16(Bw + (size_t)(n0 + row) * D + k0 + kcs * 8, Bs + chunk * 8);
    }
    __syncthreads();
#pragma unroll
    for (int kk = 0; kk < 2; kk++) {
      bf16x8 af[4], bfr[4];
#pragma unroll
      for (int mb = 0; mb < 4; mb++) {
        int row = wm * 64 + mb * 16 + (l & 15);
        int kc0 = kk * 4 + (l >> 4);
        af[mb] = *(const bf16x8*)(As + row * 64 + ((kc0 ^ (row & 7)) << 3));
      }
#pragma unroll
      for (int nb = 0; nb < 4; nb++) {
        int row = wn * 64 + nb * 16 + (l & 15);
        int kc0 = kk * 4 + (l >> 4);
        bfr[nb] = *(const bf16x8*)(Bs + row * 64 + ((kc0 ^ (row & 7)) << 3));
      }
#pragma unroll
      for (int mb = 0; mb < 4; mb++)
#pragma unroll
        for (int nb = 0; nb < 4; nb++)
          acc[mb][nb] = __builtin_amdgcn_mfma_f32_16x16x32_bf16(af[mb], bfr[nb], acc[mb][nb], 0, 0, 0);
    }
    __syncthreads();
  }

  float* ch = (float*)ldsbuf;
#pragma unroll
  for (int c = 0; c < 4; c++) {
    if (wm == (c >> 1)) {
#pragma unroll
      for (int nb = 0; nb < 4; nb++) {
        int col = wn * 64 + nb * 16 + (l & 15);
        float bl = bias ? bias[n0 + col] : 0.f;
#pragma unroll
        for (int mbi = 0; mbi < 2; mbi++) {
          int mb = (c & 1) * 2 + mbi;
#pragma unroll
          for (int q2 = 0; q2 < 4; q2++) {
            int row_local = mb * 16 + (l >> 4) * 4 + q2 - (c & 1) * 32;
            ch[row_local * 132 + col] = acc[mb][nb][q2] + bl;
          }
        }
      }
    }
    __syncthreads();
#pragma unroll
    for (int p = 0; p < 4; p++) {
      int r = p * 8 + (tid >> 5);
      int m = m0 + c * 32 + r;
      if (m < mlimit) {
        int seg = tid & 31;
        *(float4*)(outp + (size_t)m * D + n0 + seg * 4) =
            *(const float4*)(ch + r * 132 + seg * 4);
      }
    }
    __syncthreads();
  }
}

__device__ __forceinline__ void vocab_body(int bid, int tid, u16* ldsbuf,
    const u16* __restrict__ A, const u16* __restrict__ Bw,
    const float* __restrict__ blog, float* __restrict__ out) {
  u16* As = ldsbuf;
  u16* Bs = ldsbuf + 128 * 64;
  int swz = (bid & 7) * 250 + (bid >> 3);          // bijective on [0,2000)
  int m0 = (swz & 7) * 128, n0 = (swz >> 3) * 128;
  int l = tid & 63;
  int w = tid >> 6, wm = w >> 1, wn = w & 1;

  f32x4 acc[4][4];
#pragma unroll
  for (int mb = 0; mb < 4; mb++)
#pragma unroll
    for (int nb = 0; nb < 4; nb++) acc[mb][nb] = (f32x4){0.f, 0.f, 0.f, 0.f};

  for (int k0 = 0; k0 < D; k0 += 64) {
#pragma unroll
    for (int i = 0; i < 4; i++) {
      int chunk = i * 256 + tid;
      int row = chunk >> 3, kc = chunk & 7;
      int kcs = kc ^ (row & 7);
      gload_lds16(A + (size_t)(m0 + row) * D + k0 + kcs * 8, As + chunk * 8);
      gload_lds16(Bw + (size_t)(n0 + row) * D + k0 + kcs * 8, Bs + chunk * 8);
    }
    __syncthreads();
#pragma unroll
    for (int kk = 0; kk < 2; kk++) {
      bf16x8 af[4], bfr[4];
#pragma unroll
      for (int mb = 0; mb < 4; mb++) {
        int row = wm * 64 + mb * 16 + (l & 15);
        int kc0 = kk * 4 + (l >> 4);
        af[mb] = *(const bf16x8*)(As + row * 64 + ((kc0 ^ (row & 7)) << 3));
      }
#pragma unroll
      for (int nb = 0; nb < 4; nb++) {
        int row = wn * 64 + nb * 16 + (l & 15);
        int kc0 = kk * 4 + (l >> 4);
        bfr[nb] = *(const bf16x8*)(Bs + row * 64 + ((kc0 ^ (row & 7)) << 3));
      }
#pragma unroll
      for (int mb = 0; mb < 4; mb++)
#pragma unroll
        for (int nb = 0; nb < 4; nb++)
          acc[mb][nb] = __builtin_amdgcn_mfma_f32_16x16x32_bf16(af[mb], bfr[nb], acc[mb][nb], 0, 0, 0);
    }
    __syncthreads();
  }

  float* ch = (float*)ldsbuf;
#pragma unroll
  for (int c = 0; c < 4; c++) {
    if (wm == (c >> 1)) {
#pragma unroll
      for (int nb = 0; nb < 4; nb++) {
        int col = wn * 64 + nb * 16 + (l & 15);
        float bl = blog[n0 + col];
#pragma unroll
        for (int mbi = 0; mbi < 2; mbi++) {
          int mb = (c & 1) * 2 + mbi;
#pragma unroll
          for (int q2 = 0; q2 < 4; q2++) {
            int row_local = mb * 16 + (l >> 4) * 4 + q2 - (c & 1) * 32;
            ch[row_local * 132 + col] = acc[mb][nb][q2] + bl;
          }
        }
      }
    }
    __syncthreads();
#pragma unroll
    for (int p = 0; p < 4; p++) {
      int r = p * 8 + (tid >> 5);
      int m = m0 + c * 32 + r;
      if (m < BT) {
        int seg = tid & 31;
        *(float4*)(out + (size_t)m * VR + n0 + seg * 4) =
            *(const float4*)(ch + r * 132 + seg * 4);
      }
    }
    __syncthreads();
  }
}

// ---- qhgemm: qh[b,t,:] = gamma[b,t,:] @ vWqr[b] + bqr  (selgemm-style, fp32 out) ----
__device__ __forceinline__ void qhgemm_body(int bq, int tid, float* gT /*[S][TP]*/,
    const float* __restrict__ vWqr, const float* __restrict__ gammaT,
    const float* __restrict__ bqr, float* __restrict__ qh) {
  int b = bq >> 2, dc = bq & 3;
  int dl = tid & 127, th0 = tid >> 7;
  int d = dc * 128 + dl;
  for (int i = tid; i < S * TP; i += 256) {
    int r = i >> 6, c = i & 63;
    gT[r * TP + c] = gammaT[((size_t)b * S + r) * TP + c];
  }
  __syncthreads();
  float acc[2][16];
#pragma unroll
  for (int g = 0; g < 2; g++)
#pragma unroll
    for (int m = 0; m < 16; m++) acc[g][m] = 0.f;
  for (int ss = 0; ss < S; ss++) {
    float vv = vWqr[((size_t)b * S + ss) * D + d];
#pragma unroll
    for (int g = 0; g < 2; g++) {
      int tg = th0 + 2 * g;
      const float* gp = gT + ss * TP + tg * 16;
      float4 g0 = *(const float4*)gp;
      float4 g1 = *(const float4*)(gp + 4);
      float4 g2 = *(const float4*)(gp + 8);
      float4 g3 = *(const float4*)(gp + 12);
      acc[g][0]  = fmaf(g0.x, vv, acc[g][0]);  acc[g][1]  = fmaf(g0.y, vv, acc[g][1]);
      acc[g][2]  = fmaf(g0.z, vv, acc[g][2]);  acc[g][3]  = fmaf(g0.w, vv, acc[g][3]);
      acc[g][4]  = fmaf(g1.x, vv, acc[g][4]);  acc[g][5]  = fmaf(g1.y, vv, acc[g][5]);
      acc[g][6]  = fmaf(g1.z, vv, acc[g][6]);  acc[g][7]  = fmaf(g1.w, vv, acc[g][7]);
      acc[g][8]  = fmaf(g2.x, vv, acc[g][8]);  acc[g][9]  = fmaf(g2.y, vv, acc[g][9]);
      acc[g][10] = fmaf(g2.z, vv, acc[g][10]); acc[g][11] = fmaf(g2.w, vv, acc[g][11]);
      acc[g][12] = fmaf(g3.x, vv, acc[g][12]); acc[g][13] = fmaf(g3.y, vv, acc[g][13]);
      acc[g][14] = fmaf(g3.z, vv, acc[g][14]); acc[g][15] = fmaf(g3.w, vv, acc[g][15]);
    }
  }
  float bz = bqr[d];
#pragma unroll
  for (int g = 0; g < 2; g++) {
    int tg = th0 + 2 * g;
#pragma unroll
    for (int m = 0; m < 16; m++) {
      int t = tg * 16 + m;
      if (t < T) qh[((size_t)b * T + t) * D + d] = acc[g][m] + bz;
    }
  }
}

// ---- vubeta: K-chunks of 128, float4 staged, fully-unrolled independent loads ----
__device__ __forceinline__ void vubeta_body(int bq, int tid, float* sm,
    const float* __restrict__ u, const float* __restrict__ v,
    const float* __restrict__ attn, const float* __restrict__ ra,
    const float* __restrict__ addp, const float* __restrict__ ctxn,
    const float* __restrict__ vn, const float* __restrict__ bn,
    float* __restrict__ gammaT) {
  int b = bq / 5, sc = bq % 5;
  int tq = tid >> 2, sg = tid & 3;
  float* u_s = sm;               // [60][132]
  float* v_s = sm + 7920;        // [20][132]
  float* aw_s = sm + 10560;      // [60][20]
  float* ra_s = sm + 11760;
  float* vu_s = sm + 12960;
  float* gm_s = sm + 14160;
  float* ap_s = sm + 15360;
  float* cx_s = sm + 15420;
  float* vns_s = sm + 15480;
#pragma unroll
  for (int ii = 0; ii < 5; ii++) {
    int i = ii * 256 + tid;
    if (i < T * 20) {
      int t = i / 20, sl = i % 20;
      size_t base = ((size_t)b * T + t) * S + sc * 20 + sl;
      aw_s[t * 20 + sl] = attn[base];
      ra_s[t * 20 + sl] = ra[base];
    }
  }
  if (tid < T) { ap_s[tid] = addp[b * T + tid]; cx_s[tid] = ctxn[b * T + tid]; }
  if (tid >= 64 && tid < 84) vns_s[tid - 64] = vn[b * S + sc * 20 + tid - 64];

  float acc[5] = {0, 0, 0, 0, 0};
  for (int kc = 0; kc < 4; kc++) {                 // 128-wide K chunks
#pragma unroll
    for (int ii = 0; ii < 8; ii++) {
      int i = ii * 256 + tid;
      if (i < 60 * 32) {
        int r = i >> 5, c = (i & 31) * 4;
        *(float4*)&u_s[r * 132 + c] =
            *(const float4*)&u[((size_t)b * T + r) * D + kc * 128 + c];
      }
    }
#pragma unroll
    for (int ii = 0; ii < 3; ii++) {
      int i = ii * 256 + tid;
      if (i < 20 * 32) {
        int r = i >> 5, c = (i & 31) * 4;
        *(float4*)&v_s[r * 132 + c] =
            *(const float4*)&v[((size_t)b * S + sc * 20 + r) * D + kc * 128 + c];
      }
    }
    __syncthreads();
    if (tq < 60) {
#pragma unroll
      for (int e0 = 0; e0 < 128; e0 += 4) {
        float4 uu = *(const float4*)&u_s[tq * 132 + e0];
#pragma unroll
        for (int m = 0; m < 5; m++) {
          float4 vv = *(const float4*)&v_s[(sg * 5 + m) * 132 + e0];
          acc[m] = fmaf(uu.x, vv.x, acc[m]);
          acc[m] = fmaf(uu.y, vv.y, acc[m]);
          acc[m] = fmaf(uu.z, vv.z, acc[m]);
          acc[m] = fmaf(uu.w, vv.w, acc[m]);
        }
      }
    }
    __syncthreads();
  }
  if (tq < 60) {
#pragma unroll
    for (int m = 0; m < 5; m++) vu_s[tq * 20 + sg * 5 + m] = acc[m];
  }
  __syncthreads();
  if (tid < 20) {
    int s = sc * 20 + tid;
    float dec = (s < 50) ? 1.f - (float)(s + 1) / 50.f : 0.f;
    float a = dec, beta = dec;
    float vns = vns_s[tid], bnv = bn[0];
    for (int t = 0; t < T; t++) {
      float g = ap_s[t] * sigmoidf_(vns + cx_s[t] + bnv);
      float wv = (1.f - a) * g;
      a += wv;
      gm_s[t * 20 + tid] = aw_s[t * 20 + tid] * beta;   // gamma uses PRE-update beta
      beta = beta * (1.f - ra_s[t * 20 + tid] * sigmoidf_(beta * vu_s[t * 20 + tid])) + wv;
    }
  }
  __syncthreads();
#pragma unroll
  for (int ii = 0; ii < 5; ii++) {
    int i = ii * 256 + tid;
    if (i < T * 20) {
      int sl = i / 60, t = i % 60;
      gammaT[((size_t)b * S + sc * 20 + sl) * TP + t] = gm_s[t * 20 + sl];
    }
  }
}

// ---- role ----
__device__ __forceinline__ void role_body(int row, int tid, float* sc, float* pr,
    const float* __restrict__ khf, const float* __restrict__ qh,
    const float* __restrict__ pgen, float* __restrict__ out) {
  int b = row / T;
  if (tid < H * R) {
    int h = tid / R, r = tid % R;
    const float* qp = qh + (size_t)row * D + h * DK;
    const float* kp = khf + (size_t)(b * R + r) * D + h * DK;
    float acc = 0.f;
#pragma unroll
    for (int i = 0; i < DK; i++) acc = fmaf(qp[i], kp[i], acc);
    sc[tid] = acc * 0.125f;                        // 1/sqrt(64)
  }
  __syncthreads();
  if (tid < H) {
    float m = -INFINITY;
    for (int r = 0; r < R; r++) m = fmaxf(m, sc[tid * R + r]);
    float ssum = 0.f;
    for (int r = 0; r < R; r++) { float e = expf(sc[tid * R + r] - m); pr[tid * R + r] = e; ssum += e; }
    float inv = 1.f / ssum;
    for (int r = 0; r < R; r++) pr[tid * R + r] *= inv;
  }
  __syncthreads();
  if (tid < R) {
    float acc = 0.f;
#pragma unroll
    for (int h = 0; h < H; h++) acc += pr[h * R + tid];
    out[(size_t)row * VR + V + tid] = acc * (1.f / H) * pgen[row];
  }
}

// ================= dispatch kernels =================

// L1: prep (incl Wlogit/v cvt) + vn + attnscal — all input-only
__global__ __launch_bounds__(256) void k_combo1(
    const float* Wlogit, const float* q, const float* Wq, const float* f,
    const float* Wqr, const float* Wkr, const float* logits, const float* v,
    const float* Wn, const float* Wr, const float* br, const float* Wa, const float* ba,
    const float* Wptr, const float* bptr,
    u16* Wlbf, u16* qbf, u16* Wqlb, u16* fb, u16* vb, u16* qwb, u16* WqrT, u16* WkrT,
    float* vn, float* vn2, float* attn_g, float* remv, float* addp, float* pgen) {
  __shared__ float tile[64][65];
  int blk = blockIdx.x, tid = threadIdx.x;
  if (blk < NB_PREP) {
    prep_body(blk, tid, tile, Wlogit, q, Wq, f, v, Wqr, Wkr,
              Wlbf, qbf, Wqlb, fb, vb, qwb, WqrT, WkrT);
  } else if (blk < NB_PREP + 400) {
    int row = (blk - NB_PREP) * 4 + (tid >> 6);    // 1600 rows
    vn_body(row, tid & 63, v, Wn, vn, vn2);
  } else {
    int row = (blk - NB_PREP - 400) * 4 + (tid >> 6);  // 960 rows
    attnscal_body(row, tid & 63, logits, q, Wr, br, Wa, ba, Wptr, bptr,
                  attn_g, remv, addp, pgen);
  }
}

// L2: vocab [0,550) + dual gemm (44) + vWqr gemm (52) + attnw (960)
__global__ __launch_bounds__(256) void k_combo2(
    const u16* qbf, const u16* Wlbf, const float* blog, float* out,
    const u16* qwb, const u16* Wqlb, float* u,
    const u16* fb, const u16* WkrT, const float* bkr, float* khf,
    const u16* vb, const u16* WqrT, float* vWqr,
    const float* attn, const float* vn2, const float* remv, float* ra, float* ctxn) {
  __shared__ u16 lds[2 * 128 * 64];
  int blk = blockIdx.x, tid = threadIdx.x;
  if (blk < 550) {
    vocab_body(blk, tid, lds, qbf, Wlbf, blog, out);
  } else if (blk < 594) {
    int z = blk - 550, xx = z % 11, yy = z / 11;
    if (xx < 8) gemm512_body(qwb, Wqlb, nullptr, u, BT, xx, yy, tid, lds);
    else        gemm512_body(fb, WkrT, bkr, khf, B * R, xx - 8, yy, tid, lds);
  } else if (blk < 646) {
    int z = blk - 594;                             // 52 blocks: 13 x 4
    gemm512_body(vb, WqrT, nullptr, vWqr, B * S, z % 13, z / 13, tid, lds);
  } else {
    attnw_body(blk - 646, tid, (float*)lds, attn, vn2, remv, ra, ctxn);
  }
}

// L3: vubeta (80) + vocab [550,900)
__global__ __launch_bounds__(256) void k_vubetap(
    const float* u, const float* v, const float* attn, const float* ra,
    const float* addp, const float* ctxn, const float* vn, const float* bn,
    float* gammaT,
    const u16* qbf, const u16* Wlbf, const float* blog, float* out) {
  __shared__ float smem[15500];                    // 62 KB (vubeta) / vocab uses 32 KB
  int blk = blockIdx.x, tid = threadIdx.x;
  if (blk < 80) vubeta_body(blk, tid, smem, u, v, attn, ra, addp, ctxn, vn, bn, gammaT);
  else          vocab_body(550 + blk - 80, tid, (u16*)smem, qbf, Wlbf, blog, out);
}

// L4: qhgemm (64) + vocab [900,1600)
__global__ __launch_bounds__(256) void k_combo3(
    const u16* qbf, const u16* Wlbf, const float* blog, float* out,
    const float* vWqr, const float* gammaT, const float* bqr, float* qh) {
  __shared__ u16 lds[2 * 128 * 64];
  int blk = blockIdx.x, tid = threadIdx.x;
  if (blk < 700) vocab_body(900 + blk, tid, lds, qbf, Wlbf, blog, out);
  else           qhgemm_body(blk - 700, tid, (float*)lds, vWqr, gammaT, bqr, qh);
}

// L5: role (960) + vocab [1600,2000)
__global__ __launch_bounds__(256) void k_rolep(
    const float* khf, const float* qh, const float* pgen, float* out,
    const u16* qbf, const u16* Wlbf, const float* blog) {
  __shared__ u16 lds[2 * 128 * 64];
  int blk = blockIdx.x, tid = threadIdx.x;
  if (blk < 400) {
    vocab_body(1600 + blk, tid, lds, qbf, Wlbf, blog, out);
  } else {
    float* sc = (float*)lds;
    float* pr = sc + H * R;
    role_body(blk - 400, tid, sc, pr, khf, qh, pgen, out);
  }
}

extern "C" void kernel_launch(void* const* d_in, const int* in_sizes, int n_in,
                              void* d_out, int out_size, void* d_ws, size_t ws_size,
                              hipStream_t stream) {
  const float* v_out  = (const float*)d_in[0];
  const float* f_out  = (const float*)d_in[1];
  const float* q_seq  = (const float*)d_in[2];
  const float* logits = (const float*)d_in[3];
  const float* Wr     = (const float*)d_in[4];
  const float* br     = (const float*)d_in[5];
  const float* Wa     = (const float*)d_in[6];
  const float* ba     = (const float*)d_in[7];
  const float* Wq_lin = (const float*)d_in[8];
  const float* Wn     = (const float*)d_in[9];
  const float* bn     = (const float*)d_in[10];
  const float* Wlogit = (const float*)d_in[11];
  const float* blogit = (const float*)d_in[12];
  const float* Wptr   = (const float*)d_in[13];
  const float* bptr   = (const float*)d_in[14];
  const float* Wqr    = (const float*)d_in[15];
  const float* bqr    = (const float*)d_in[16];
  const float* Wkr    = (const float*)d_in[17];
  const float* bkr    = (const float*)d_in[18];
  float* out = (float*)d_out;
  float* ws  = (float*)d_ws;

  float* attn   = ws;                                  // BT*S
  float* ra     = attn   + (size_t)BT * S;             // BT*S
  float* u      = ra     + (size_t)BT * S;             // BT*D
  float* pgen   = u      + (size_t)BT * D;             // BT
  float* remv   = pgen   + BT;                         // BT
  float* addp   = remv   + BT;                         // BT
  float* ctxn   = addp   + BT;                         // BT
  float* vn     = ctxn   + BT;                         // B*S
  float* vn2    = vn     + B * S;                      // B*S
  float* khf    = vn2    + B * S;                      // B*R*D
  float* qh     = khf    + (size_t)B * R * D;          // BT*D
  float* gammaT = qh     + (size_t)BT * D;             // B*S*TP
  float* vWqr   = gammaT + (size_t)B * S * TP;         // B*S*D
  u16*   qwb    = (u16*)(vWqr + (size_t)B * S * D);    // MP*D
  u16*   vb     = qwb  + (size_t)MP * D;               // VBP*D
  u16*   fb     = vb   + (size_t)VBP * D;              // FP*D
  u16*   Wqlb   = fb   + (size_t)FP * D;               // D*D
  u16*   WqrT   = Wqlb + (size_t)D * D;                // D*D
  u16*   WkrT   = WqrT + (size_t)D * D;                // D*D
  u16*   qbf    = WkrT + (size_t)D * D;                // MP*D
  u16*   Wlbf   = qbf  + (size_t)MP * D;               // V*D

  // L1: all input-only work
  k_combo1<<<NB_PREP + 400 + 240, 256, 0, stream>>>(
      Wlogit, q_seq, Wq_lin, f_out, Wqr, Wkr, logits, v_out,
      Wn, Wr, br, Wa, ba, Wptr, bptr,
      Wlbf, qbf, Wqlb, fb, vb, qwb, WqrT, WkrT,
      vn, vn2, attn, remv, addp, pgen);

  // L2: vocab 550 + u/kh GEMMs + vWqr GEMM + attnw
  k_combo2<<<550 + 44 + 52 + 960, 256, 0, stream>>>(
      qbf, Wlbf, blogit, out, qwb, Wqlb, u, fb, WkrT, bkr, khf,
      vb, WqrT, vWqr, attn, vn2, remv, ra, ctxn);

  // L3: vubeta + vocab 350
  k_vubetap<<<80 + 350, 256, 0, stream>>>(
      u, v_out, attn, ra, addp, ctxn, vn, bn, gammaT, qbf, Wlbf, blogit, out);

  // L4: vocab 700 + qhgemm (qh = gamma @ vWqr + bqr; selgemm+qh-GEMM eliminated)
  k_combo3<<<700 + B * 4, 256, 0, stream>>>(qbf, Wlbf, blogit, out, vWqr, gammaT, bqr, qh);

  // L5: vocab 400 + role epilogue
  k_rolep<<<400 + BT, 256, 0, stream>>>(khf, qh, pgen, out, qbf, Wlbf, blogit);
}